// Round 10
// baseline (496.626 us; speedup 1.0000x reference)
//
#include <hip/hip_runtime.h>

typedef unsigned short u16;
typedef unsigned int   u32;
typedef __bf16 bf16;
typedef bf16  bf16x8 __attribute__((ext_vector_type(8)));
typedef float f32x4  __attribute__((ext_vector_type(4)));

__device__ __forceinline__ u16 bf16u(float f) {
    u32 x = __builtin_bit_cast(u32, f);
    x += 0x7fffu + ((x >> 16) & 1u);   // RNE
    return (u16)(x >> 16);
}

__device__ __forceinline__ void gl_lds16(const void* g, void* l) {
    __builtin_amdgcn_global_load_lds(
        (const __attribute__((address_space(1))) u32*)g,
        (__attribute__((address_space(3))) u32*)l, 16, 0, 0);
}

// ---------------- fp32 -> bf16 convert (vectorized) ----------------
__global__ __launch_bounds__(256) void cvt_x_kernel(const float4* __restrict__ in,
                                                    ushort4* __restrict__ out, int n4) {
    int i = blockIdx.x * 256 + threadIdx.x;
    if (i >= n4) return;
    float4 f = in[i];
    ushort4 o;
    o.x = bf16u(f.x); o.y = bf16u(f.y); o.z = bf16u(f.z); o.w = bf16u(f.w);
    out[i] = o;
}

// ------- all 4 weight transposes in one kernel (fp32 W -> bf16 W^T) --------
__global__ __launch_bounds__(256) void transp_all(
    const float* __restrict__ Wq, const float* __restrict__ Wk,
    const float* __restrict__ Wv, const float* __restrict__ Wo,
    u16* __restrict__ WqkvT, u16* __restrict__ WoT)
{
    const int z = blockIdx.z;
    const float* W; u16* WT; int rows, cols;
    if (z < 3) {
        if (blockIdx.y >= 32) return;
        W = (z == 0) ? Wq : (z == 1) ? Wk : Wv;
        WT = WqkvT + (size_t)z * 1024 * 1024;
        rows = 1024; cols = 1024;
    } else {
        W = Wo; WT = WoT; rows = 2048; cols = 1024;
    }
    __shared__ float t[32][33];
    int bx = blockIdx.x * 32, by = blockIdx.y * 32;
    int x = threadIdx.x & 31, y = threadIdx.x >> 5;
#pragma unroll
    for (int i = 0; i < 32; i += 8)
        t[y + i][x] = W[(size_t)(by + y + i) * cols + bx + x];
    __syncthreads();
#pragma unroll
    for (int i = 0; i < 32; i += 8)
        WT[(size_t)(bx + y + i) * rows + by + x] = bf16u(t[x][y + i]);
}

// == 128x128 GEMM: A via LDS (m97 serial), B DIRECT global->VGPR (reg dbuf) ==
// C[M][N] = A[M][K]*BT[N][K]^T. 256 thr = 4 waves (2M x 2N), wave tile 64x64.
// LDS: A only, [128][32] bf16 = 8 KB single buffer -> LDS pipe/step: 16
// ds_read + 8KB writes ~= 256 cy < MFMA 296 cy (first MFMA-heavy config).
// B frags (BT[col][k], col-major-K): 16B/lane contiguous -> 4 global bf16x8
// loads per wave-step, L2/L3-resident weights, 2-deep register double-buffer
// issued one step early (latency under MFMA + A-stage).
// Per step: [sync] stageA(t) + loadB(t+1) [sync=vmcnt0: A&B landed] 4 ds_read,
// 16 MFMA. Co-resident blocks (3/CU) cover the serial stage latency (m114).
// A chunk swizzle (r7/r9-verified, 0 conflicts): slot s at row r holds global
// k-chunk s^((r>>1)&3); inverse on gl_lds SOURCE, forward on ds_read (rule 21).
// mode 1: bf16 out + fused RoPE when col<2048.  mode 2: fp32 out.
__global__ __launch_bounds__(256, 3) void gemm_bd(
    const u16* __restrict__ A, const u16* __restrict__ BT, void* __restrict__ Cout,
    const float* __restrict__ cosp, const float* __restrict__ sinp,
    int M, int N, int K, int mode)
{
    __shared__ u16 Ld[4096];       // A only: 128 rows x 32k bf16
    const int tid = threadIdx.x;
    const int wid = tid >> 6, lane = tid & 63;
    const int nx = gridDim.x;
    const int nwg = nx * gridDim.y;
    const int orig = blockIdx.y * nx + blockIdx.x;
    const int vid = (orig & 7) * (nwg >> 3) + (orig >> 3);
    const int m0 = (vid / nx) << 7, n0 = (vid % nx) << 7;
    const int wr = wid >> 1, wc = wid & 1;

    // ---- A staging (r9 pattern, halved): thread covers chunks tid, tid+256 ----
    const int srow = tid >> 2;                       // 0..63
    const int sg = (tid & 3) ^ ((srow >> 1) & 3);    // inverse-swizzled k-chunk
    const u16* aS = A + (size_t)(m0 + srow) * K + (sg << 3);
    const size_t h64K = (size_t)64 * K;
    const int wdb = wid << 9;                        // wave-uniform dest (u16)
    const int nt = K >> 5;

    // ---- B direct-load bases: col = n0 + wc*64 + ni*16 + (lane&15) ----
    const u16* Bb = BT + (size_t)(n0 + (wc << 6) + (lane & 15)) * K
                       + ((lane >> 4) << 3);
    const size_t bstep = (size_t)16 * K;             // ni stride

    // ---- A frag reads: row base + i*16 + (lane&15); phys chunk swizzled ----
    const int phys = ((lane >> 4) ^ ((lane >> 1) & 3)) << 3;
    const int raw = ((wr << 6) + (lane & 15)) << 5;  // u16 offset

    f32x4 acc[4][4] = {};
    bf16x8 b0[4], b1[4];

#define STAGEA(T) do { const size_t _ko = (size_t)(T) << 5; \
        gl_lds16(aS + _ko,        &Ld[wdb]); \
        gl_lds16(aS + _ko + h64K, &Ld[2048 + wdb]); } while (0)
#define LOADB(DST, T) do { const size_t _ko = (size_t)(T) << 5; \
        DST[0] = *(const bf16x8*)(Bb + _ko); \
        DST[1] = *(const bf16x8*)(Bb + bstep + _ko); \
        DST[2] = *(const bf16x8*)(Bb + 2 * bstep + _ko); \
        DST[3] = *(const bf16x8*)(Bb + 3 * bstep + _ko); } while (0)
#define COMPUTE(BREG) do { \
        bf16x8 af[4]; \
        _Pragma("unroll") \
        for (int i = 0; i < 4; i++) \
            af[i] = *(const bf16x8*)&Ld[raw + (i << 9) + phys]; \
        __builtin_amdgcn_s_setprio(1); \
        _Pragma("unroll") \
        for (int mi = 0; mi < 4; mi++) \
            _Pragma("unroll") \
            for (int ni = 0; ni < 4; ni++) \
                acc[mi][ni] = __builtin_amdgcn_mfma_f32_16x16x32_bf16( \
                    af[mi], BREG[ni], acc[mi][ni], 0, 0, 0); \
        __builtin_amdgcn_s_setprio(0); } while (0)

    LOADB(b0, 0);
    for (int t = 0; t < nt; t += 2) {
        // even step: compute with b0, prefetch b1
        if (t) __syncthreads();          // readers of tile t-1 done
        STAGEA(t);
        if (t + 1 < nt) LOADB(b1, t + 1);
        __syncthreads();                 // vmcnt(0): A tile t (and b1) landed
        COMPUTE(b0);
        // odd step: compute with b1, prefetch b0
        __syncthreads();
        STAGEA(t + 1);
        if (t + 2 < nt) LOADB(b0, t + 2);
        __syncthreads();
        COMPUTE(b1);
    }
#undef STAGEA
#undef LOADB
#undef COMPUTE

    const int colbase = n0 + (wc << 6) + (lane & 15);
    if (mode == 2) {
        float* C = (float*)Cout;
#pragma unroll
        for (int mi = 0; mi < 4; mi++)
#pragma unroll
            for (int r = 0; r < 4; r++) {
                int m = m0 + (wr << 6) + (mi << 4) + ((lane >> 4) << 2) + r;
                float* row = C + (size_t)m * N + colbase;
#pragma unroll
                for (int ni = 0; ni < 4; ni++) row[ni << 4] = acc[mi][ni][r];
            }
    } else if (n0 < 2048) {                   // fused QKV: RoPE region (Q and K)
        u16* C = (u16*)Cout;
#pragma unroll
        for (int mi = 0; mi < 4; mi++)
#pragma unroll
            for (int r = 0; r < 4; r++) {
                int m = m0 + (wr << 6) + (mi << 4) + ((lane >> 4) << 2) + r;
                const float* cb = cosp + ((size_t)m << 6);
                const float* sb = sinp + ((size_t)m << 6);
                u16* row = C + (size_t)m * N + colbase;
#pragma unroll
                for (int ni = 0; ni < 4; ni++) {
                    int d = (ni << 4) + (lane & 15);   // head-dim pos (0..63)
                    float c = cb[d], s = sb[d];
                    float v0 = acc[mi][ni][r];
                    float vr = acc[mi][ni ^ 2][r];     // d +/- 32 partner
                    float o = fmaf(v0, c, (ni < 2 ? -vr : vr) * s);
                    row[ni << 4] = bf16u(o);
                }
            }
    } else {                                  // V region: plain bf16
        u16* C = (u16*)Cout;
#pragma unroll
        for (int mi = 0; mi < 4; mi++)
#pragma unroll
            for (int r = 0; r < 4; r++) {
                int m = m0 + (wr << 6) + (mi << 4) + ((lane >> 4) << 2) + r;
                u16* row = C + (size_t)m * N + colbase;
#pragma unroll
                for (int ni = 0; ni < 4; ni++) row[ni << 4] = bf16u(acc[mi][ni][r]);
            }
    }
}

// ------- axial attention, both passes in one launch (4096 blocks) ----------
// qkv: (16384 x 3072) bf16 [q|k|v]. blocks [0,2048) = width, [2048,4096) = height.
__global__ __launch_bounds__(256) void axial_attn(
    const u16* __restrict__ qkv, const float* __restrict__ mask,
    u16* __restrict__ cat)
{
    __shared__ u16 Kl[128 * 64];    // XOR-swizzled 16B chunks (^ row&7)
    __shared__ u16 VT[64 * 128];    // V^T, swizzled (^ d&15)
    __shared__ u16 Pl[128 * 128];   // P (q-major), swizzled (^ q&15)
    const int hmode = blockIdx.x >> 11;
    const int o2 = blockIdx.x & 2047;
    const int b = (o2 & 7) * 256 + (o2 >> 3);   // per-half XCD chunk swizzle
    const int a = b >> 4, hd = b & 15;
    const int tid = threadIdx.x, wid = tid >> 6, lane = tid & 63;
    const int tmul = hmode ? 128 : 1;
    const int tadd = hmode ? a : (a << 7);
    const size_t hoff = (size_t)hd << 6;

#pragma unroll
    for (int c = 0; c < 4; c++) {
        int row = (wid << 5) + (c << 3) + (lane >> 3);
        int sc = (lane & 7) ^ (row & 7);
        gl_lds16(qkv + (size_t)(row * tmul + tadd) * 3072 + 1024 + hoff + (sc << 3),
                 &Kl[((wid << 5) + (c << 3)) << 6]);
    }
#pragma unroll
    for (int i = 0; i < 4; i++) {
        int cid = tid + (i << 8);
        int j = cid >> 3;
        int d0 = (cid & 7) << 3;
        uint4 raw = *(const uint4*)(qkv + (size_t)(j * tmul + tadd) * 3072 + 2048 + hoff + d0);
        const u16* e = (const u16*)&raw;
#pragma unroll
        for (int t = 0; t < 8; t++) {
            int d = d0 + t;
            VT[(d << 7) + (((j >> 3) ^ (d & 15)) << 3) + (j & 7)] = e[t];
        }
    }
    bf16x8 aq[2][2];
#pragma unroll
    for (int qt = 0; qt < 2; qt++)
#pragma unroll
        for (int ks = 0; ks < 2; ks++) {
            int row = (wid << 5) + (qt << 4) + (lane & 15);
            aq[qt][ks] = *(const bf16x8*)(qkv + (size_t)(row * tmul + tadd) * 3072 + hoff
                                          + (ks << 5) + ((lane >> 4) << 3));
        }
    __syncthreads();

    f32x4 S[2][8] = {};
#pragma unroll
    for (int kt = 0; kt < 8; kt++) {
        bf16x8 bk[2];
#pragma unroll
        for (int ks = 0; ks < 2; ks++) {
            int row = (kt << 4) + (lane & 15);
            int ch = ((ks << 2) + (lane >> 4)) ^ (row & 7);
            bk[ks] = *(const bf16x8*)&Kl[(row << 6) + (ch << 3)];
        }
#pragma unroll
        for (int qt = 0; qt < 2; qt++) {
            S[qt][kt] = __builtin_amdgcn_mfma_f32_16x16x32_bf16(aq[qt][0], bk[0], S[qt][kt], 0, 0, 0);
            S[qt][kt] = __builtin_amdgcn_mfma_f32_16x16x32_bf16(aq[qt][1], bk[1], S[qt][kt], 0, 0, 0);
        }
    }

    const float scale = 0.03125f;   // 1/sqrt(1024)
#pragma unroll
    for (int qt = 0; qt < 2; qt++) {
#pragma unroll
        for (int r = 0; r < 4; r++) {
            int qrow = (wid << 5) + (qt << 4) + ((lane >> 4) << 2) + r;
            const float* mrow = mask + (hmode ? (a << 7) : (qrow << 7));
            float mx = -1e30f;
#pragma unroll
            for (int kt = 0; kt < 8; kt++) {
                float sv = fmaf(S[qt][kt][r], scale, mrow[(kt << 4) + (lane & 15)]);
                S[qt][kt][r] = sv;
                mx = fmaxf(mx, sv);
            }
            mx = fmaxf(mx, __shfl_xor(mx, 1));
            mx = fmaxf(mx, __shfl_xor(mx, 2));
            mx = fmaxf(mx, __shfl_xor(mx, 4));
            mx = fmaxf(mx, __shfl_xor(mx, 8));
            float sum = 0.f;
#pragma unroll
            for (int kt = 0; kt < 8; kt++) {
                float p = __expf(S[qt][kt][r] - mx);
                S[qt][kt][r] = p;
                sum += p;
            }
            sum += __shfl_xor(sum, 1);
            sum += __shfl_xor(sum, 2);
            sum += __shfl_xor(sum, 4);
            sum += __shfl_xor(sum, 8);
            float rinv = 1.0f / sum;
#pragma unroll
            for (int kt = 0; kt < 8; kt++) {
                int kcol = (kt << 4) + (lane & 15);
                int ch = (kcol >> 3) ^ (qrow & 15);
                Pl[(qrow << 7) + (ch << 3) + (kcol & 7)] = bf16u(S[qt][kt][r] * rinv);
            }
        }
    }
    __syncthreads();

    f32x4 O[4][2] = {};
#pragma unroll
    for (int ks = 0; ks < 4; ks++) {
        bf16x8 av[4], bp[2];
#pragma unroll
        for (int dt = 0; dt < 4; dt++) {
            int drow = (dt << 4) + (lane & 15);
            int ch = ((ks << 2) + (lane >> 4)) ^ (drow & 15);
            av[dt] = *(const bf16x8*)&VT[(drow << 7) + (ch << 3)];
        }
#pragma unroll
        for (int qt = 0; qt < 2; qt++) {
            int qrow = (wid << 5) + (qt << 4) + (lane & 15);
            int ch = ((ks << 2) + (lane >> 4)) ^ (qrow & 15);
            bp[qt] = *(const bf16x8*)&Pl[(qrow << 7) + (ch << 3)];
        }
#pragma unroll
        for (int dt = 0; dt < 4; dt++)
#pragma unroll
            for (int qt = 0; qt < 2; qt++)
                O[dt][qt] = __builtin_amdgcn_mfma_f32_16x16x32_bf16(av[dt], bp[qt], O[dt][qt], 0, 0, 0);
    }

    const int cbase = (hmode ? 1024 : 0) + (hd << 6);
#pragma unroll
    for (int dt = 0; dt < 4; dt++)
#pragma unroll
        for (int qt = 0; qt < 2; qt++) {
            int qrow = (wid << 5) + (qt << 4) + (lane & 15);
            int d0 = (dt << 4) + ((lane >> 4) << 2);
            size_t base = ((size_t)(qrow * tmul + tadd) << 11) + cbase + d0;
            ushort4 pk;
            pk.x = bf16u(O[dt][qt][0]);
            pk.y = bf16u(O[dt][qt][1]);
            pk.z = bf16u(O[dt][qt][2]);
            pk.w = bf16u(O[dt][qt][3]);
            *(ushort4*)(cat + base) = pk;
        }
}

extern "C" void kernel_launch(void* const* d_in, const int* in_sizes, int n_in,
                              void* d_out, int out_size, void* d_ws, size_t ws_size,
                              hipStream_t stream)
{
    (void)in_sizes; (void)n_in; (void)out_size; (void)ws_size;
    const float* hidden = (const float*)d_in[0];
    const float* mask   = (const float*)d_in[1];
    const float* cosp   = (const float*)d_in[2];
    const float* sinp   = (const float*)d_in[3];
    const float* Wq     = (const float*)d_in[4];
    const float* Wk     = (const float*)d_in[5];
    const float* Wv     = (const float*)d_in[6];
    const float* Wo     = (const float*)d_in[7];

    char* ws = (char*)d_ws;
    u16* Xb    = (u16*)(ws);                  // 33,554,432 B
    u16* WqkvT = (u16*)(ws + 33554432);       //  6,291,456 B
    u16* cat   = (u16*)(ws);                  // 67,108,864 B (reuse, stream-ordered)
    u16* WoT   = (u16*)(ws + 67108864);       //  4,194,304 B
    u16* qkvb  = (u16*)(ws + 71303168);       // 100,663,296 B

    cvt_x_kernel<<<16384, 256, 0, stream>>>((const float4*)hidden, (ushort4*)Xb, 4194304);
    transp_all<<<dim3(32, 64, 4), 256, 0, stream>>>(Wq, Wk, Wv, Wo, WqkvT, WoT);

    // fused QKV projection + RoPE: [16384,1024] x [1024,3072]
    gemm_bd<<<dim3(24, 128), 256, 0, stream>>>(Xb, WqkvT, qkvb, cosp, sinp, 16384, 3072, 1024, 1);

    axial_attn<<<4096, 256, 0, stream>>>(qkvb, mask, cat);

    // output projection: [16384,2048] x [2048,1024] -> fp32
    gemm_bd<<<dim3(8, 128), 256, 0, stream>>>(cat, WoT, d_out, nullptr, nullptr, 16384, 1024, 2048, 2);
}

// Round 11
// 331.075 us; speedup vs baseline: 1.5000x; 1.5000x over previous
//
#include <hip/hip_runtime.h>

typedef unsigned short u16;
typedef unsigned int   u32;
typedef __bf16 bf16;
typedef bf16  bf16x8 __attribute__((ext_vector_type(8)));
typedef float f32x4  __attribute__((ext_vector_type(4)));

__device__ __forceinline__ u16 bf16u(float f) {
    u32 x = __builtin_bit_cast(u32, f);
    x += 0x7fffu + ((x >> 16) & 1u);   // RNE
    return (u16)(x >> 16);
}

__device__ __forceinline__ void gl_lds16(const void* g, void* l) {
    __builtin_amdgcn_global_load_lds(
        (const __attribute__((address_space(1))) u32*)g,
        (__attribute__((address_space(3))) u32*)l, 16, 0, 0);
}

// ---------------- fp32 -> bf16 convert (vectorized) ----------------
__global__ __launch_bounds__(256) void cvt_x_kernel(const float4* __restrict__ in,
                                                    ushort4* __restrict__ out, int n4) {
    int i = blockIdx.x * 256 + threadIdx.x;
    if (i >= n4) return;
    float4 f = in[i];
    ushort4 o;
    o.x = bf16u(f.x); o.y = bf16u(f.y); o.z = bf16u(f.z); o.w = bf16u(f.w);
    out[i] = o;
}

// ------- all 4 weight transposes in one kernel (fp32 W -> bf16 W^T) --------
__global__ __launch_bounds__(256) void transp_all(
    const float* __restrict__ Wq, const float* __restrict__ Wk,
    const float* __restrict__ Wv, const float* __restrict__ Wo,
    u16* __restrict__ WqkvT, u16* __restrict__ WoT)
{
    const int z = blockIdx.z;
    const float* W; u16* WT; int rows, cols;
    if (z < 3) {
        if (blockIdx.y >= 32) return;
        W = (z == 0) ? Wq : (z == 1) ? Wk : Wv;
        WT = WqkvT + (size_t)z * 1024 * 1024;
        rows = 1024; cols = 1024;
    } else {
        W = Wo; WT = WoT; rows = 2048; cols = 1024;
    }
    __shared__ float t[32][33];
    int bx = blockIdx.x * 32, by = blockIdx.y * 32;
    int x = threadIdx.x & 31, y = threadIdx.x >> 5;
#pragma unroll
    for (int i = 0; i < 32; i += 8)
        t[y + i][x] = W[(size_t)(by + y + i) * cols + bx + x];
    __syncthreads();
#pragma unroll
    for (int i = 0; i < 32; i += 8)
        WT[(size_t)(bx + y + i) * rows + by + x] = bf16u(t[x][y + i]);
}

// ====== 128x128 GEMM, pair-step: 4x16KB bufs, barrier-pair per 2 K-steps ====
// C[M][N] = A[M][K]*BT[N][K]^T. 256 thr = 4 waves (2M x 2N), wave tile 64x64.
// LDS 64 KB -> 2 blocks/CU co-resident (m114 overlap).
// Pair (t, t+1): [BAR] stage(t+2)->buf[(t+2)&3], stage(t+3)->buf[(t+3)&3];
//   reads(t)+16 MFMA; reads(t+1)+16 MFMA  (both bufs pre-published -> compiler
//   may overlap reads(t+1) with MFMA(t) — first variant where ds_read can hide
//   under MFMA); VM0 (stages landed; full-pair slack); [BAR].
// Rotation safety: buf[(t+2)&3]=buf[(t-2)&3], buf[(t+3)&3]=buf[(t-1)&3]; both
// were last read in the PREVIOUS pair, whose reads completed before this
// pair's opening barrier. Single-stage-ordering per pair; vmcnt(0) publish.
// A/B chunk swizzle (r7/r9-verified, 0 conflicts): LDS slot s at row r holds
// global k-chunk s^((r>>1)&3); inverse on gl_lds SOURCE, forward on ds_read.
// mode 1: bf16 out + fused RoPE when col<2048.  mode 2: fp32 out.
#define BAR   __builtin_amdgcn_s_barrier()
#define VM0   asm volatile("s_waitcnt vmcnt(0)" ::: "memory")

__global__ __launch_bounds__(256, 2) void gemm_pp(
    const u16* __restrict__ A, const u16* __restrict__ BT, void* __restrict__ Cout,
    const float* __restrict__ cosp, const float* __restrict__ sinp,
    int M, int N, int K, int mode)
{
    __shared__ u16 Ld[4][8192];    // per buf: A @0 (4096 u16), B @4096 = 16 KB
    const int tid = threadIdx.x;
    const int wid = tid >> 6, lane = tid & 63;
    const int nx = gridDim.x;
    const int nwg = nx * gridDim.y;
    const int orig = blockIdx.y * nx + blockIdx.x;
    const int vid = (orig & 7) * (nwg >> 3) + (orig >> 3);
    const int m0 = (vid / nx) << 7, n0 = (vid % nx) << 7;
    const int wr = wid >> 1, wc = wid & 1;

    // staging (r9 pattern): thread covers 16B-chunks tid (rows 0-63), tid+256
    const int srow = tid >> 2;                       // 0..63
    const int sg = (tid & 3) ^ ((srow >> 1) & 3);    // inverse-swizzled k-chunk
    const u16* aS = A + (size_t)(m0 + srow) * K + (sg << 3);
    const u16* bS = BT + (size_t)(n0 + srow) * K + (sg << 3);
    const size_t h64K = (size_t)64 * K;
    const int wdb = wid << 9;                        // wave-uniform dest (u16)
    const int nt = K >> 5;                           // even (K % 64 == 0)

#define STAGE(T) do { const int _b = (T) & 3; const size_t _ko = (size_t)(T) << 5; \
        gl_lds16(aS + _ko,        &Ld[_b][wdb]); \
        gl_lds16(aS + _ko + h64K, &Ld[_b][2048 + wdb]); \
        gl_lds16(bS + _ko,        &Ld[_b][4096 + wdb]); \
        gl_lds16(bS + _ko + h64K, &Ld[_b][6144 + wdb]); } while (0)

    // frag reads: row = base + i*16 + (lane&15); phys = (lane>>4)^((lane>>1)&3)
    const int phys = ((lane >> 4) ^ ((lane >> 1) & 3)) << 3;
    const int raw = ((wr << 6) + (lane & 15)) << 5;          // A row base (u16)
    const int rbw = (((wc << 6) + (lane & 15)) << 5) + 4096; // B row base (u16)

    f32x4 acc[4][4] = {};

    STAGE(0); STAGE(1);
    VM0; BAR;

    for (int t = 0; t < nt; t += 2) {
        if (t + 2 < nt) STAGE(t + 2);
        if (t + 3 < nt) STAGE(t + 3);
        {   // ---- K-step t ----
            const u16* Lb = &Ld[t & 3][0];
            bf16x8 af[4], bfr[4];
#pragma unroll
            for (int i = 0; i < 4; i++)
                af[i] = *(const bf16x8*)&Lb[raw + (i << 9) + phys];
#pragma unroll
            for (int i = 0; i < 4; i++)
                bfr[i] = *(const bf16x8*)&Lb[rbw + (i << 9) + phys];
            __builtin_amdgcn_s_setprio(1);
#pragma unroll
            for (int mi = 0; mi < 4; mi++)
#pragma unroll
                for (int ni = 0; ni < 4; ni++)
                    acc[mi][ni] = __builtin_amdgcn_mfma_f32_16x16x32_bf16(
                        af[mi], bfr[ni], acc[mi][ni], 0, 0, 0);
            __builtin_amdgcn_s_setprio(0);
        }
        {   // ---- K-step t+1 (buffer pre-published; reads may overlap above) ----
            const u16* Lb = &Ld[(t + 1) & 3][0];
            bf16x8 af[4], bfr[4];
#pragma unroll
            for (int i = 0; i < 4; i++)
                af[i] = *(const bf16x8*)&Lb[raw + (i << 9) + phys];
#pragma unroll
            for (int i = 0; i < 4; i++)
                bfr[i] = *(const bf16x8*)&Lb[rbw + (i << 9) + phys];
            __builtin_amdgcn_s_setprio(1);
#pragma unroll
            for (int mi = 0; mi < 4; mi++)
#pragma unroll
                for (int ni = 0; ni < 4; ni++)
                    acc[mi][ni] = __builtin_amdgcn_mfma_f32_16x16x32_bf16(
                        af[mi], bfr[ni], acc[mi][ni], 0, 0, 0);
            __builtin_amdgcn_s_setprio(0);
        }
        VM0; BAR;
    }
#undef STAGE

    const int colbase = n0 + (wc << 6) + (lane & 15);
    if (mode == 2) {
        float* C = (float*)Cout;
#pragma unroll
        for (int mi = 0; mi < 4; mi++)
#pragma unroll
            for (int r = 0; r < 4; r++) {
                int m = m0 + (wr << 6) + (mi << 4) + ((lane >> 4) << 2) + r;
                float* row = C + (size_t)m * N + colbase;
#pragma unroll
                for (int ni = 0; ni < 4; ni++) row[ni << 4] = acc[mi][ni][r];
            }
    } else if (n0 < 2048) {                   // fused QKV: RoPE region (Q and K)
        u16* C = (u16*)Cout;
#pragma unroll
        for (int mi = 0; mi < 4; mi++)
#pragma unroll
            for (int r = 0; r < 4; r++) {
                int m = m0 + (wr << 6) + (mi << 4) + ((lane >> 4) << 2) + r;
                const float* cb = cosp + ((size_t)m << 6);
                const float* sb = sinp + ((size_t)m << 6);
                u16* row = C + (size_t)m * N + colbase;
#pragma unroll
                for (int ni = 0; ni < 4; ni++) {
                    int d = (ni << 4) + (lane & 15);   // head-dim pos (0..63)
                    float c = cb[d], s = sb[d];
                    float v0 = acc[mi][ni][r];
                    float vr = acc[mi][ni ^ 2][r];     // d +/- 32 partner
                    float o = fmaf(v0, c, (ni < 2 ? -vr : vr) * s);
                    row[ni << 4] = bf16u(o);
                }
            }
    } else {                                  // V region: plain bf16
        u16* C = (u16*)Cout;
#pragma unroll
        for (int mi = 0; mi < 4; mi++)
#pragma unroll
            for (int r = 0; r < 4; r++) {
                int m = m0 + (wr << 6) + (mi << 4) + ((lane >> 4) << 2) + r;
                u16* row = C + (size_t)m * N + colbase;
#pragma unroll
                for (int ni = 0; ni < 4; ni++) row[ni << 4] = bf16u(acc[mi][ni][r]);
            }
    }
}

// ------- axial attention, both passes in one launch (4096 blocks) ----------
// qkv: (16384 x 3072) bf16 [q|k|v]. blocks [0,2048) = width, [2048,4096) = height.
__global__ __launch_bounds__(256) void axial_attn(
    const u16* __restrict__ qkv, const float* __restrict__ mask,
    u16* __restrict__ cat)
{
    __shared__ u16 Kl[128 * 64];    // XOR-swizzled 16B chunks (^ row&7)
    __shared__ u16 VT[64 * 128];    // V^T, swizzled (^ d&15)
    __shared__ u16 Pl[128 * 128];   // P (q-major), swizzled (^ q&15)
    const int hmode = blockIdx.x >> 11;
    const int o2 = blockIdx.x & 2047;
    const int b = (o2 & 7) * 256 + (o2 >> 3);   // per-half XCD chunk swizzle
    const int a = b >> 4, hd = b & 15;
    const int tid = threadIdx.x, wid = tid >> 6, lane = tid & 63;
    const int tmul = hmode ? 128 : 1;
    const int tadd = hmode ? a : (a << 7);
    const size_t hoff = (size_t)hd << 6;

#pragma unroll
    for (int c = 0; c < 4; c++) {
        int row = (wid << 5) + (c << 3) + (lane >> 3);
        int sc = (lane & 7) ^ (row & 7);
        gl_lds16(qkv + (size_t)(row * tmul + tadd) * 3072 + 1024 + hoff + (sc << 3),
                 &Kl[((wid << 5) + (c << 3)) << 6]);
    }
#pragma unroll
    for (int i = 0; i < 4; i++) {
        int cid = tid + (i << 8);
        int j = cid >> 3;
        int d0 = (cid & 7) << 3;
        uint4 raw = *(const uint4*)(qkv + (size_t)(j * tmul + tadd) * 3072 + 2048 + hoff + d0);
        const u16* e = (const u16*)&raw;
#pragma unroll
        for (int t = 0; t < 8; t++) {
            int d = d0 + t;
            VT[(d << 7) + (((j >> 3) ^ (d & 15)) << 3) + (j & 7)] = e[t];
        }
    }
    bf16x8 aq[2][2];
#pragma unroll
    for (int qt = 0; qt < 2; qt++)
#pragma unroll
        for (int ks = 0; ks < 2; ks++) {
            int row = (wid << 5) + (qt << 4) + (lane & 15);
            aq[qt][ks] = *(const bf16x8*)(qkv + (size_t)(row * tmul + tadd) * 3072 + hoff
                                          + (ks << 5) + ((lane >> 4) << 3));
        }
    __syncthreads();

    f32x4 S[2][8] = {};
#pragma unroll
    for (int kt = 0; kt < 8; kt++) {
        bf16x8 bk[2];
#pragma unroll
        for (int ks = 0; ks < 2; ks++) {
            int row = (kt << 4) + (lane & 15);
            int ch = ((ks << 2) + (lane >> 4)) ^ (row & 7);
            bk[ks] = *(const bf16x8*)&Kl[(row << 6) + (ch << 3)];
        }
#pragma unroll
        for (int qt = 0; qt < 2; qt++) {
            S[qt][kt] = __builtin_amdgcn_mfma_f32_16x16x32_bf16(aq[qt][0], bk[0], S[qt][kt], 0, 0, 0);
            S[qt][kt] = __builtin_amdgcn_mfma_f32_16x16x32_bf16(aq[qt][1], bk[1], S[qt][kt], 0, 0, 0);
        }
    }

    const float scale = 0.03125f;   // 1/sqrt(1024)
#pragma unroll
    for (int qt = 0; qt < 2; qt++) {
#pragma unroll
        for (int r = 0; r < 4; r++) {
            int qrow = (wid << 5) + (qt << 4) + ((lane >> 4) << 2) + r;
            const float* mrow = mask + (hmode ? (a << 7) : (qrow << 7));
            float mx = -1e30f;
#pragma unroll
            for (int kt = 0; kt < 8; kt++) {
                float sv = fmaf(S[qt][kt][r], scale, mrow[(kt << 4) + (lane & 15)]);
                S[qt][kt][r] = sv;
                mx = fmaxf(mx, sv);
            }
            mx = fmaxf(mx, __shfl_xor(mx, 1));
            mx = fmaxf(mx, __shfl_xor(mx, 2));
            mx = fmaxf(mx, __shfl_xor(mx, 4));
            mx = fmaxf(mx, __shfl_xor(mx, 8));
            float sum = 0.f;
#pragma unroll
            for (int kt = 0; kt < 8; kt++) {
                float p = __expf(S[qt][kt][r] - mx);
                S[qt][kt][r] = p;
                sum += p;
            }
            sum += __shfl_xor(sum, 1);
            sum += __shfl_xor(sum, 2);
            sum += __shfl_xor(sum, 4);
            sum += __shfl_xor(sum, 8);
            float rinv = 1.0f / sum;
#pragma unroll
            for (int kt = 0; kt < 8; kt++) {
                int kcol = (kt << 4) + (lane & 15);
                int ch = (kcol >> 3) ^ (qrow & 15);
                Pl[(qrow << 7) + (ch << 3) + (kcol & 7)] = bf16u(S[qt][kt][r] * rinv);
            }
        }
    }
    __syncthreads();

    f32x4 O[4][2] = {};
#pragma unroll
    for (int ks = 0; ks < 4; ks++) {
        bf16x8 av[4], bp[2];
#pragma unroll
        for (int dt = 0; dt < 4; dt++) {
            int drow = (dt << 4) + (lane & 15);
            int ch = ((ks << 2) + (lane >> 4)) ^ (drow & 15);
            av[dt] = *(const bf16x8*)&VT[(drow << 7) + (ch << 3)];
        }
#pragma unroll
        for (int qt = 0; qt < 2; qt++) {
            int qrow = (wid << 5) + (qt << 4) + (lane & 15);
            int ch = ((ks << 2) + (lane >> 4)) ^ (qrow & 15);
            bp[qt] = *(const bf16x8*)&Pl[(qrow << 7) + (ch << 3)];
        }
#pragma unroll
        for (int dt = 0; dt < 4; dt++)
#pragma unroll
            for (int qt = 0; qt < 2; qt++)
                O[dt][qt] = __builtin_amdgcn_mfma_f32_16x16x32_bf16(av[dt], bp[qt], O[dt][qt], 0, 0, 0);
    }

    const int cbase = (hmode ? 1024 : 0) + (hd << 6);
#pragma unroll
    for (int dt = 0; dt < 4; dt++)
#pragma unroll
        for (int qt = 0; qt < 2; qt++) {
            int qrow = (wid << 5) + (qt << 4) + (lane & 15);
            int d0 = (dt << 4) + ((lane >> 4) << 2);
            size_t base = ((size_t)(qrow * tmul + tadd) << 11) + cbase + d0;
            ushort4 pk;
            pk.x = bf16u(O[dt][qt][0]);
            pk.y = bf16u(O[dt][qt][1]);
            pk.z = bf16u(O[dt][qt][2]);
            pk.w = bf16u(O[dt][qt][3]);
            *(ushort4*)(cat + base) = pk;
        }
}

extern "C" void kernel_launch(void* const* d_in, const int* in_sizes, int n_in,
                              void* d_out, int out_size, void* d_ws, size_t ws_size,
                              hipStream_t stream)
{
    (void)in_sizes; (void)n_in; (void)out_size; (void)ws_size;
    const float* hidden = (const float*)d_in[0];
    const float* mask   = (const float*)d_in[1];
    const float* cosp   = (const float*)d_in[2];
    const float* sinp   = (const float*)d_in[3];
    const float* Wq     = (const float*)d_in[4];
    const float* Wk     = (const float*)d_in[5];
    const float* Wv     = (const float*)d_in[6];
    const float* Wo     = (const float*)d_in[7];

    char* ws = (char*)d_ws;
    u16* Xb    = (u16*)(ws);                  // 33,554,432 B
    u16* WqkvT = (u16*)(ws + 33554432);       //  6,291,456 B
    u16* cat   = (u16*)(ws);                  // 67,108,864 B (reuse, stream-ordered)
    u16* WoT   = (u16*)(ws + 67108864);       //  4,194,304 B
    u16* qkvb  = (u16*)(ws + 71303168);       // 100,663,296 B

    cvt_x_kernel<<<16384, 256, 0, stream>>>((const float4*)hidden, (ushort4*)Xb, 4194304);
    transp_all<<<dim3(32, 64, 4), 256, 0, stream>>>(Wq, Wk, Wv, Wo, WqkvT, WoT);

    // fused QKV projection + RoPE: [16384,1024] x [1024,3072]
    gemm_pp<<<dim3(24, 128), 256, 0, stream>>>(Xb, WqkvT, qkvb, cosp, sinp, 16384, 3072, 1024, 1);

    axial_attn<<<4096, 256, 0, stream>>>(qkvb, mask, cat);

    // output projection: [16384,2048] x [2048,1024] -> fp32
    gemm_pp<<<dim3(8, 128), 256, 0, stream>>>(cat, WoT, d_out, nullptr, nullptr, 16384, 1024, 2048, 2);
}

// Round 12
// 325.273 us; speedup vs baseline: 1.5268x; 1.0178x over previous
//
#include <hip/hip_runtime.h>

typedef unsigned short u16;
typedef unsigned int   u32;
typedef __bf16 bf16;
typedef bf16  bf16x8 __attribute__((ext_vector_type(8)));
typedef float f32x4  __attribute__((ext_vector_type(4)));

__device__ __forceinline__ u16 bf16u(float f) {
    u32 x = __builtin_bit_cast(u32, f);
    x += 0x7fffu + ((x >> 16) & 1u);   // RNE
    return (u16)(x >> 16);
}

__device__ __forceinline__ void gl_lds16(const void* g, void* l) {
    __builtin_amdgcn_global_load_lds(
        (const __attribute__((address_space(1))) u32*)g,
        (__attribute__((address_space(3))) u32*)l, 16, 0, 0);
}

// ---- merged prep: fp32->bf16 convert (z==4) + 4 weight transposes (z<4) ----
__global__ __launch_bounds__(256) void prep_all(
    const float* __restrict__ hidden, ushort4* __restrict__ Xb,
    const float* __restrict__ Wq, const float* __restrict__ Wk,
    const float* __restrict__ Wv, const float* __restrict__ Wo,
    u16* __restrict__ WqkvT, u16* __restrict__ WoT)
{
    const int z = blockIdx.z;
    if (z == 4) {   // cvt: 2048 blocks x 8 float4-chunks of 256
        const float4* in = (const float4*)hidden;
        int b = blockIdx.y * 32 + blockIdx.x;
#pragma unroll
        for (int it = 0; it < 8; it++) {
            int i = (b << 11) + (it << 8) + threadIdx.x;
            float4 f = in[i];
            ushort4 o;
            o.x = bf16u(f.x); o.y = bf16u(f.y); o.z = bf16u(f.z); o.w = bf16u(f.w);
            Xb[i] = o;
        }
        return;
    }
    const float* W; u16* WT; int rows, cols;
    if (z < 3) {
        if (blockIdx.y >= 32) return;
        W = (z == 0) ? Wq : (z == 1) ? Wk : Wv;
        WT = WqkvT + (size_t)z * 1024 * 1024;
        rows = 1024; cols = 1024;
    } else {
        W = Wo; WT = WoT; rows = 2048; cols = 1024;
    }
    __shared__ float t[32][33];
    int bx = blockIdx.x * 32, by = blockIdx.y * 32;
    int x = threadIdx.x & 31, y = threadIdx.x >> 5;
#pragma unroll
    for (int i = 0; i < 32; i += 8)
        t[y + i][x] = W[(size_t)(by + y + i) * cols + bx + x];
    __syncthreads();
#pragma unroll
    for (int i = 0; i < 32; i += 8)
        WT[(size_t)(bx + y + i) * rows + by + x] = bf16u(t[x][y + i]);
}

// ==== 128x128 GEMM, BK=64 single-buffer serial, 32KB LDS -> 5 blocks/CU ====
// C[M][N] = A[M][K]*BT[N][K]^T. 256 thr = 4 waves (2M x 2N), wave tile 64x64.
// LDS: A[128][64] @0 + B[128][64] @8192 (u16) = 32 KB, single buffer.
// Window t (K-slab of 64): [sync] stage 32KB (8 gl_lds/wave) [sync=vmcnt0]
//   kk=0: 8 ds_read + 16 MFMA; kk=1: 8 ds_read + 16 MFMA  (frag regs reused).
// Half the barrier windows of BK=32 variants; 5 co-resident blocks/CU cover
// each window's stage drain + barrier skew (m114).
// Swizzle: row r (stride 128B = 8 chunks) stores global k-chunk g at slot
// s = g ^ (r&7); inverse applied on the gl_lds SOURCE (linear dest, rule 21);
// reads use phys = (kk*4 + (lane>>4)) ^ (lane&7) -> 8 distinct banksets per
// 8 rows, 2-way residual = free (m136).
// mode 1: bf16 out + fused RoPE when col<2048.  mode 2: fp32 out.
__global__ __launch_bounds__(256) void gemm_sb(
    const u16* __restrict__ A, const u16* __restrict__ BT, void* __restrict__ Cout,
    const float* __restrict__ cosp, const float* __restrict__ sinp,
    int M, int N, int K, int mode)
{
    __shared__ u16 Ld[16384];      // A @0 (8192 u16), B @8192
    const int tid = threadIdx.x;
    const int wid = tid >> 6, lane = tid & 63;
    const int nx = gridDim.x;
    const int nwg = nx * gridDim.y;
    const int orig = blockIdx.y * nx + blockIdx.x;
    const int vid = (orig & 7) * (nwg >> 3) + (orig >> 3);
    const int m0 = (vid / nx) << 7, n0 = (vid % nx) << 7;
    const int wr = wid >> 1, wc = wid & 1;

    // staging: wave wid, instr i (0..3): lane covers linear chunk
    // wid*256 + i*64 + lane; row = chunk>>3, slot = chunk&7, g = slot^(row&7).
    const int crow0 = (wid << 5) + (lane >> 3);      // i=0 row; +8 per i
    const int sg0 = (lane & 7);
    const size_t rK[4] = {
        (size_t)(crow0) * K,       (size_t)(crow0 + 8) * K,
        (size_t)(crow0 + 16) * K,  (size_t)(crow0 + 24) * K };
    int gsl[4];
#pragma unroll
    for (int i = 0; i < 4; i++) gsl[i] = (sg0 ^ ((crow0 + 8 * i) & 7)) << 3;
    const u16* aB = A + (size_t)m0 * K;
    const u16* bB = BT + (size_t)n0 * K;
    const int dstA = (wid << 11);                    // u16 idx, +512 per i
    const int nt = K >> 6;

    // frag reads: phys chunk = (kk*4 + (lane>>4)) ^ (lane&7)
    const int ph0 = (((lane >> 4))     ^ (lane & 7)) << 3;
    const int ph1 = (((lane >> 4) + 4) ^ (lane & 7)) << 3;
    const int raw = ((wr << 6) + (lane & 15)) << 6;          // A row base (u16)
    const int rbw = (((wc << 6) + (lane & 15)) << 6) + 8192; // B row base (u16)

    f32x4 acc[4][4] = {};

    for (int t = 0; t < nt; ++t) {
        if (t) __syncthreads();          // readers of slab t-1 done
        const size_t ko = (size_t)t << 6;
#pragma unroll
        for (int i = 0; i < 4; i++)
            gl_lds16(aB + rK[i] + ko + gsl[i], &Ld[dstA + (i << 9)]);
#pragma unroll
        for (int i = 0; i < 4; i++)
            gl_lds16(bB + rK[i] + ko + gsl[i], &Ld[8192 + dstA + (i << 9)]);
        __syncthreads();                 // drains vmcnt(0): slab t in LDS

        bf16x8 af[4], bfr[4];
#pragma unroll
        for (int i = 0; i < 4; i++)
            af[i] = *(const bf16x8*)&Ld[raw + (i << 10) + ph0];
#pragma unroll
        for (int i = 0; i < 4; i++)
            bfr[i] = *(const bf16x8*)&Ld[rbw + (i << 10) + ph0];
        __builtin_amdgcn_s_setprio(1);
#pragma unroll
        for (int mi = 0; mi < 4; mi++)
#pragma unroll
            for (int ni = 0; ni < 4; ni++)
                acc[mi][ni] = __builtin_amdgcn_mfma_f32_16x16x32_bf16(
                    af[mi], bfr[ni], acc[mi][ni], 0, 0, 0);
        __builtin_amdgcn_s_setprio(0);
#pragma unroll
        for (int i = 0; i < 4; i++)
            af[i] = *(const bf16x8*)&Ld[raw + (i << 10) + ph1];
#pragma unroll
        for (int i = 0; i < 4; i++)
            bfr[i] = *(const bf16x8*)&Ld[rbw + (i << 10) + ph1];
        __builtin_amdgcn_s_setprio(1);
#pragma unroll
        for (int mi = 0; mi < 4; mi++)
#pragma unroll
            for (int ni = 0; ni < 4; ni++)
                acc[mi][ni] = __builtin_amdgcn_mfma_f32_16x16x32_bf16(
                    af[mi], bfr[ni], acc[mi][ni], 0, 0, 0);
        __builtin_amdgcn_s_setprio(0);
    }

    const int colbase = n0 + (wc << 6) + (lane & 15);
    if (mode == 2) {
        float* C = (float*)Cout;
#pragma unroll
        for (int mi = 0; mi < 4; mi++)
#pragma unroll
            for (int r = 0; r < 4; r++) {
                int m = m0 + (wr << 6) + (mi << 4) + ((lane >> 4) << 2) + r;
                float* row = C + (size_t)m * N + colbase;
#pragma unroll
                for (int ni = 0; ni < 4; ni++) row[ni << 4] = acc[mi][ni][r];
            }
    } else if (n0 < 2048) {                   // fused QKV: RoPE region (Q and K)
        u16* C = (u16*)Cout;
#pragma unroll
        for (int mi = 0; mi < 4; mi++)
#pragma unroll
            for (int r = 0; r < 4; r++) {
                int m = m0 + (wr << 6) + (mi << 4) + ((lane >> 4) << 2) + r;
                const float* cb = cosp + ((size_t)m << 6);
                const float* sb = sinp + ((size_t)m << 6);
                u16* row = C + (size_t)m * N + colbase;
#pragma unroll
                for (int ni = 0; ni < 4; ni++) {
                    int d = (ni << 4) + (lane & 15);   // head-dim pos (0..63)
                    float c = cb[d], s = sb[d];
                    float v0 = acc[mi][ni][r];
                    float vr = acc[mi][ni ^ 2][r];     // d +/- 32 partner
                    float o = fmaf(v0, c, (ni < 2 ? -vr : vr) * s);
                    row[ni << 4] = bf16u(o);
                }
            }
    } else {                                  // V region: plain bf16
        u16* C = (u16*)Cout;
#pragma unroll
        for (int mi = 0; mi < 4; mi++)
#pragma unroll
            for (int r = 0; r < 4; r++) {
                int m = m0 + (wr << 6) + (mi << 4) + ((lane >> 4) << 2) + r;
                u16* row = C + (size_t)m * N + colbase;
#pragma unroll
                for (int ni = 0; ni < 4; ni++) row[ni << 4] = bf16u(acc[mi][ni][r]);
            }
    }
}

// ------- axial attention, both passes in one launch (4096 blocks) ----------
// qkv: (16384 x 3072) bf16 [q|k|v]. blocks [0,2048) = width, [2048,4096) = height.
__global__ __launch_bounds__(256) void axial_attn(
    const u16* __restrict__ qkv, const float* __restrict__ mask,
    u16* __restrict__ cat)
{
    __shared__ u16 Kl[128 * 64];    // XOR-swizzled 16B chunks (^ row&7)
    __shared__ u16 VT[64 * 128];    // V^T, swizzled (^ d&15)
    __shared__ u16 Pl[128 * 128];   // P (q-major), swizzled (^ q&15)
    const int hmode = blockIdx.x >> 11;
    const int o2 = blockIdx.x & 2047;
    const int b = (o2 & 7) * 256 + (o2 >> 3);   // per-half XCD chunk swizzle
    const int a = b >> 4, hd = b & 15;
    const int tid = threadIdx.x, wid = tid >> 6, lane = tid & 63;
    const int tmul = hmode ? 128 : 1;
    const int tadd = hmode ? a : (a << 7);
    const size_t hoff = (size_t)hd << 6;

#pragma unroll
    for (int c = 0; c < 4; c++) {
        int row = (wid << 5) + (c << 3) + (lane >> 3);
        int sc = (lane & 7) ^ (row & 7);
        gl_lds16(qkv + (size_t)(row * tmul + tadd) * 3072 + 1024 + hoff + (sc << 3),
                 &Kl[((wid << 5) + (c << 3)) << 6]);
    }
#pragma unroll
    for (int i = 0; i < 4; i++) {
        int cid = tid + (i << 8);
        int j = cid >> 3;
        int d0 = (cid & 7) << 3;
        uint4 raw = *(const uint4*)(qkv + (size_t)(j * tmul + tadd) * 3072 + 2048 + hoff + d0);
        const u16* e = (const u16*)&raw;
#pragma unroll
        for (int t = 0; t < 8; t++) {
            int d = d0 + t;
            VT[(d << 7) + (((j >> 3) ^ (d & 15)) << 3) + (j & 7)] = e[t];
        }
    }
    bf16x8 aq[2][2];
#pragma unroll
    for (int qt = 0; qt < 2; qt++)
#pragma unroll
        for (int ks = 0; ks < 2; ks++) {
            int row = (wid << 5) + (qt << 4) + (lane & 15);
            aq[qt][ks] = *(const bf16x8*)(qkv + (size_t)(row * tmul + tadd) * 3072 + hoff
                                          + (ks << 5) + ((lane >> 4) << 3));
        }
    __syncthreads();

    f32x4 S[2][8] = {};
#pragma unroll
    for (int kt = 0; kt < 8; kt++) {
        bf16x8 bk[2];
#pragma unroll
        for (int ks = 0; ks < 2; ks++) {
            int row = (kt << 4) + (lane & 15);
            int ch = ((ks << 2) + (lane >> 4)) ^ (row & 7);
            bk[ks] = *(const bf16x8*)&Kl[(row << 6) + (ch << 3)];
        }
#pragma unroll
        for (int qt = 0; qt < 2; qt++) {
            S[qt][kt] = __builtin_amdgcn_mfma_f32_16x16x32_bf16(aq[qt][0], bk[0], S[qt][kt], 0, 0, 0);
            S[qt][kt] = __builtin_amdgcn_mfma_f32_16x16x32_bf16(aq[qt][1], bk[1], S[qt][kt], 0, 0, 0);
        }
    }

    const float scale = 0.03125f;   // 1/sqrt(1024)
#pragma unroll
    for (int qt = 0; qt < 2; qt++) {
#pragma unroll
        for (int r = 0; r < 4; r++) {
            int qrow = (wid << 5) + (qt << 4) + ((lane >> 4) << 2) + r;
            const float* mrow = mask + (hmode ? (a << 7) : (qrow << 7));
            float mx = -1e30f;
#pragma unroll
            for (int kt = 0; kt < 8; kt++) {
                float sv = fmaf(S[qt][kt][r], scale, mrow[(kt << 4) + (lane & 15)]);
                S[qt][kt][r] = sv;
                mx = fmaxf(mx, sv);
            }
            mx = fmaxf(mx, __shfl_xor(mx, 1));
            mx = fmaxf(mx, __shfl_xor(mx, 2));
            mx = fmaxf(mx, __shfl_xor(mx, 4));
            mx = fmaxf(mx, __shfl_xor(mx, 8));
            float sum = 0.f;
#pragma unroll
            for (int kt = 0; kt < 8; kt++) {
                float p = __expf(S[qt][kt][r] - mx);
                S[qt][kt][r] = p;
                sum += p;
            }
            sum += __shfl_xor(sum, 1);
            sum += __shfl_xor(sum, 2);
            sum += __shfl_xor(sum, 4);
            sum += __shfl_xor(sum, 8);
            float rinv = 1.0f / sum;
#pragma unroll
            for (int kt = 0; kt < 8; kt++) {
                int kcol = (kt << 4) + (lane & 15);
                int ch = (kcol >> 3) ^ (qrow & 15);
                Pl[(qrow << 7) + (ch << 3) + (kcol & 7)] = bf16u(S[qt][kt][r] * rinv);
            }
        }
    }
    __syncthreads();

    f32x4 O[4][2] = {};
#pragma unroll
    for (int ks = 0; ks < 4; ks++) {
        bf16x8 av[4], bp[2];
#pragma unroll
        for (int dt = 0; dt < 4; dt++) {
            int drow = (dt << 4) + (lane & 15);
            int ch = ((ks << 2) + (lane >> 4)) ^ (drow & 15);
            av[dt] = *(const bf16x8*)&VT[(drow << 7) + (ch << 3)];
        }
#pragma unroll
        for (int qt = 0; qt < 2; qt++) {
            int qrow = (wid << 5) + (qt << 4) + (lane & 15);
            int ch = ((ks << 2) + (lane >> 4)) ^ (qrow & 15);
            bp[qt] = *(const bf16x8*)&Pl[(qrow << 7) + (ch << 3)];
        }
#pragma unroll
        for (int dt = 0; dt < 4; dt++)
#pragma unroll
            for (int qt = 0; qt < 2; qt++)
                O[dt][qt] = __builtin_amdgcn_mfma_f32_16x16x32_bf16(av[dt], bp[qt], O[dt][qt], 0, 0, 0);
    }

    const int cbase = (hmode ? 1024 : 0) + (hd << 6);
#pragma unroll
    for (int dt = 0; dt < 4; dt++)
#pragma unroll
        for (int qt = 0; qt < 2; qt++) {
            int qrow = (wid << 5) + (qt << 4) + (lane & 15);
            int d0 = (dt << 4) + ((lane >> 4) << 2);
            size_t base = ((size_t)(qrow * tmul + tadd) << 11) + cbase + d0;
            ushort4 pk;
            pk.x = bf16u(O[dt][qt][0]);
            pk.y = bf16u(O[dt][qt][1]);
            pk.z = bf16u(O[dt][qt][2]);
            pk.w = bf16u(O[dt][qt][3]);
            *(ushort4*)(cat + base) = pk;
        }
}

extern "C" void kernel_launch(void* const* d_in, const int* in_sizes, int n_in,
                              void* d_out, int out_size, void* d_ws, size_t ws_size,
                              hipStream_t stream)
{
    (void)in_sizes; (void)n_in; (void)out_size; (void)ws_size;
    const float* hidden = (const float*)d_in[0];
    const float* mask   = (const float*)d_in[1];
    const float* cosp   = (const float*)d_in[2];
    const float* sinp   = (const float*)d_in[3];
    const float* Wq     = (const float*)d_in[4];
    const float* Wk     = (const float*)d_in[5];
    const float* Wv     = (const float*)d_in[6];
    const float* Wo     = (const float*)d_in[7];

    char* ws = (char*)d_ws;
    u16* Xb    = (u16*)(ws);                  // 33,554,432 B
    u16* WqkvT = (u16*)(ws + 33554432);       //  6,291,456 B
    u16* cat   = (u16*)(ws);                  // 67,108,864 B (reuse, stream-ordered)
    u16* WoT   = (u16*)(ws + 67108864);       //  4,194,304 B
    u16* qkvb  = (u16*)(ws + 71303168);       // 100,663,296 B

    prep_all<<<dim3(32, 64, 5), 256, 0, stream>>>(hidden, (ushort4*)Xb,
                                                  Wq, Wk, Wv, Wo, WqkvT, WoT);

    // fused QKV projection + RoPE: [16384,1024] x [1024,3072]
    gemm_sb<<<dim3(24, 128), 256, 0, stream>>>(Xb, WqkvT, qkvb, cosp, sinp, 16384, 3072, 1024, 1);

    axial_attn<<<4096, 256, 0, stream>>>(qkvb, mask, cat);

    // output projection: [16384,2048] x [2048,1024] -> fp32
    gemm_sb<<<dim3(8, 128), 256, 0, stream>>>(cat, WoT, d_out, nullptr, nullptr, 16384, 1024, 2048, 2);
}

// Round 13
// 322.772 us; speedup vs baseline: 1.5386x; 1.0077x over previous
//
#include <hip/hip_runtime.h>

typedef unsigned short u16;
typedef unsigned int   u32;
typedef __bf16 bf16;
typedef bf16  bf16x8 __attribute__((ext_vector_type(8)));
typedef float f32x4  __attribute__((ext_vector_type(4)));

__device__ __forceinline__ u16 bf16u(float f) {
    u32 x = __builtin_bit_cast(u32, f);
    x += 0x7fffu + ((x >> 16) & 1u);   // RNE
    return (u16)(x >> 16);
}

__device__ __forceinline__ void gl_lds16(const void* g, void* l) {
    __builtin_amdgcn_global_load_lds(
        (const __attribute__((address_space(1))) u32*)g,
        (__attribute__((address_space(3))) u32*)l, 16, 0, 0);
}

// ---- merged prep: fp32->bf16 convert (z==4) + 4 weight transposes (z<4) ----
__global__ __launch_bounds__(256) void prep_all(
    const float* __restrict__ hidden, ushort4* __restrict__ Xb,
    const float* __restrict__ Wq, const float* __restrict__ Wk,
    const float* __restrict__ Wv, const float* __restrict__ Wo,
    u16* __restrict__ WqkvT, u16* __restrict__ WoT)
{
    const int z = blockIdx.z;
    if (z == 4) {   // cvt: 2048 blocks x 8 float4-chunks of 256
        const float4* in = (const float4*)hidden;
        int b = blockIdx.y * 32 + blockIdx.x;
#pragma unroll
        for (int it = 0; it < 8; it++) {
            int i = (b << 11) + (it << 8) + threadIdx.x;
            float4 f = in[i];
            ushort4 o;
            o.x = bf16u(f.x); o.y = bf16u(f.y); o.z = bf16u(f.z); o.w = bf16u(f.w);
            Xb[i] = o;
        }
        return;
    }
    const float* W; u16* WT; int rows, cols;
    if (z < 3) {
        if (blockIdx.y >= 32) return;
        W = (z == 0) ? Wq : (z == 1) ? Wk : Wv;
        WT = WqkvT + (size_t)z * 1024 * 1024;
        rows = 1024; cols = 1024;
    } else {
        W = Wo; WT = WoT; rows = 2048; cols = 1024;
    }
    __shared__ float t[32][33];
    int bx = blockIdx.x * 32, by = blockIdx.y * 32;
    int x = threadIdx.x & 31, y = threadIdx.x >> 5;
#pragma unroll
    for (int i = 0; i < 32; i += 8)
        t[y + i][x] = W[(size_t)(by + y + i) * cols + bx + x];
    __syncthreads();
#pragma unroll
    for (int i = 0; i < 32; i += 8)
        WT[(size_t)(bx + y + i) * rows + by + x] = bf16u(t[x][y + i]);
}

#define BAR   __builtin_amdgcn_s_barrier()
#define SB0   __builtin_amdgcn_sched_barrier(0)
#define VM4   asm volatile("s_waitcnt vmcnt(4)" ::: "memory")
#define VM0   asm volatile("s_waitcnt vmcnt(0)" ::: "memory")

// ====== 128x128 GEMM, pair-step (r11, measured 151.4us QKV) ======
// 4x16KB bufs, barrier-pair per 2 K-steps, 2 blocks/CU. Details: r11 header.
__global__ __launch_bounds__(256, 2) void gemm_pp(
    const u16* __restrict__ A, const u16* __restrict__ BT, void* __restrict__ Cout,
    const float* __restrict__ cosp, const float* __restrict__ sinp,
    int M, int N, int K, int mode)
{
    __shared__ u16 Ld[4][8192];    // per buf: A @0 (4096 u16), B @4096 = 16 KB
    const int tid = threadIdx.x;
    const int wid = tid >> 6, lane = tid & 63;
    const int nx = gridDim.x;
    const int nwg = nx * gridDim.y;
    const int orig = blockIdx.y * nx + blockIdx.x;
    const int vid = (orig & 7) * (nwg >> 3) + (orig >> 3);
    const int m0 = (vid / nx) << 7, n0 = (vid % nx) << 7;
    const int wr = wid >> 1, wc = wid & 1;

    const int srow = tid >> 2;                       // 0..63
    const int sg = (tid & 3) ^ ((srow >> 1) & 3);    // inverse-swizzled k-chunk
    const u16* aS = A + (size_t)(m0 + srow) * K + (sg << 3);
    const u16* bS = BT + (size_t)(n0 + srow) * K + (sg << 3);
    const size_t h64K = (size_t)64 * K;
    const int wdb = wid << 9;                        // wave-uniform dest (u16)
    const int nt = K >> 5;                           // even

#define STAGE(T) do { const int _b = (T) & 3; const size_t _ko = (size_t)(T) << 5; \
        gl_lds16(aS + _ko,        &Ld[_b][wdb]); \
        gl_lds16(aS + _ko + h64K, &Ld[_b][2048 + wdb]); \
        gl_lds16(bS + _ko,        &Ld[_b][4096 + wdb]); \
        gl_lds16(bS + _ko + h64K, &Ld[_b][6144 + wdb]); } while (0)

    const int phys = ((lane >> 4) ^ ((lane >> 1) & 3)) << 3;
    const int raw = ((wr << 6) + (lane & 15)) << 5;          // A row base (u16)
    const int rbw = (((wc << 6) + (lane & 15)) << 5) + 4096; // B row base (u16)

    f32x4 acc[4][4] = {};

    STAGE(0); STAGE(1);
    VM0; BAR;

    for (int t = 0; t < nt; t += 2) {
        if (t + 2 < nt) STAGE(t + 2);
        if (t + 3 < nt) STAGE(t + 3);
        {   // ---- K-step t ----
            const u16* Lb = &Ld[t & 3][0];
            bf16x8 af[4], bfr[4];
#pragma unroll
            for (int i = 0; i < 4; i++)
                af[i] = *(const bf16x8*)&Lb[raw + (i << 9) + phys];
#pragma unroll
            for (int i = 0; i < 4; i++)
                bfr[i] = *(const bf16x8*)&Lb[rbw + (i << 9) + phys];
            __builtin_amdgcn_s_setprio(1);
#pragma unroll
            for (int mi = 0; mi < 4; mi++)
#pragma unroll
                for (int ni = 0; ni < 4; ni++)
                    acc[mi][ni] = __builtin_amdgcn_mfma_f32_16x16x32_bf16(
                        af[mi], bfr[ni], acc[mi][ni], 0, 0, 0);
            __builtin_amdgcn_s_setprio(0);
        }
        {   // ---- K-step t+1 (buffer pre-published; reads may overlap above) ----
            const u16* Lb = &Ld[(t + 1) & 3][0];
            bf16x8 af[4], bfr[4];
#pragma unroll
            for (int i = 0; i < 4; i++)
                af[i] = *(const bf16x8*)&Lb[raw + (i << 9) + phys];
#pragma unroll
            for (int i = 0; i < 4; i++)
                bfr[i] = *(const bf16x8*)&Lb[rbw + (i << 9) + phys];
            __builtin_amdgcn_s_setprio(1);
#pragma unroll
            for (int mi = 0; mi < 4; mi++)
#pragma unroll
                for (int ni = 0; ni < 4; ni++)
                    acc[mi][ni] = __builtin_amdgcn_mfma_f32_16x16x32_bf16(
                        af[mi], bfr[ni], acc[mi][ni], 0, 0, 0);
            __builtin_amdgcn_s_setprio(0);
        }
        VM0; BAR;
    }
#undef STAGE

    const int colbase = n0 + (wc << 6) + (lane & 15);
    if (mode == 2) {
        float* C = (float*)Cout;
#pragma unroll
        for (int mi = 0; mi < 4; mi++)
#pragma unroll
            for (int r = 0; r < 4; r++) {
                int m = m0 + (wr << 6) + (mi << 4) + ((lane >> 4) << 2) + r;
                float* row = C + (size_t)m * N + colbase;
#pragma unroll
                for (int ni = 0; ni < 4; ni++) row[ni << 4] = acc[mi][ni][r];
            }
    } else if (n0 < 2048) {                   // fused QKV: RoPE region (Q and K)
        u16* C = (u16*)Cout;
#pragma unroll
        for (int mi = 0; mi < 4; mi++)
#pragma unroll
            for (int r = 0; r < 4; r++) {
                int m = m0 + (wr << 6) + (mi << 4) + ((lane >> 4) << 2) + r;
                const float* cb = cosp + ((size_t)m << 6);
                const float* sb = sinp + ((size_t)m << 6);
                u16* row = C + (size_t)m * N + colbase;
#pragma unroll
                for (int ni = 0; ni < 4; ni++) {
                    int d = (ni << 4) + (lane & 15);   // head-dim pos (0..63)
                    float c = cb[d], s = sb[d];
                    float v0 = acc[mi][ni][r];
                    float vr = acc[mi][ni ^ 2][r];     // d +/- 32 partner
                    float o = fmaf(v0, c, (ni < 2 ? -vr : vr) * s);
                    row[ni << 4] = bf16u(o);
                }
            }
    } else {                                  // V region: plain bf16
        u16* C = (u16*)Cout;
#pragma unroll
        for (int mi = 0; mi < 4; mi++)
#pragma unroll
            for (int r = 0; r < 4; r++) {
                int m = m0 + (wr << 6) + (mi << 4) + ((lane >> 4) << 2) + r;
                u16* row = C + (size_t)m * N + colbase;
#pragma unroll
                for (int ni = 0; ni < 4; ni++) row[ni << 4] = bf16u(acc[mi][ni][r]);
            }
    }
}

// ====== 256x256 GEMM, fat-phase 3-buffer (r7, best Wo ~103us) ======
// 512 thr = 8 waves (2M x 4N), wave 128x64; BK=32; 96 KB LDS. Details: r7 hdr.
__global__ __launch_bounds__(512, 2) void gemm_fat(
    const u16* __restrict__ A, const u16* __restrict__ BT, void* __restrict__ Cout,
    const float* __restrict__ cosp, const float* __restrict__ sinp,
    int M, int N, int K, int mode)
{
    __shared__ u16 Ld[3][16384];   // per buf: A @0 (8192 u16), B @8192
    const int tid = threadIdx.x;
    const int wid = tid >> 6, lane = tid & 63;
    const int nx = gridDim.x;
    const int nwg = nx * gridDim.y;
    const int orig = blockIdx.y * nx + blockIdx.x;
    const int vid = (orig & 7) * (nwg >> 3) + (orig >> 3);
    const int m0 = (vid / nx) << 8, n0 = (vid % nx) << 8;
    const int wr = wid >> 2, wc = wid & 3;

    const int srow = tid >> 2;                     // row 0..127
    const int sl = (tid & 3) ^ ((srow >> 1) & 3);  // inverse-swizzled chunk
    const u16* aS0 = A + (size_t)(m0 + srow) * K + (sl << 3);
    const u16* aS1 = aS0 + (size_t)128 * K;
    const u16* bS0 = BT + (size_t)(n0 + srow) * K + (sl << 3);
    const u16* bS1 = bS0 + (size_t)128 * K;
    const int wdb = wid << 9;                      // wave-uniform dest (u16)
    const int nt = K >> 5;

#define STAGE(T, B_) do { if ((T) < nt) { size_t _ko = (size_t)(T) << 5; \
        gl_lds16(aS0 + _ko, &Ld[B_][wdb]); \
        gl_lds16(aS1 + _ko, &Ld[B_][4096 + wdb]); \
        gl_lds16(bS0 + _ko, &Ld[B_][8192 + wdb]); \
        gl_lds16(bS1 + _ko, &Ld[B_][12288 + wdb]); } } while (0)

    const int phys = ((lane >> 4) ^ ((lane >> 1) & 3)) << 3;   // u16 offset
    const int raw = ((wr << 7) + (lane & 15)) << 5;            // A row base (u16)
    const int rbw = (((wc << 6) + (lane & 15)) << 5) + 8192;   // B row base (u16)

    f32x4 acc[8][4] = {};

    STAGE(0, 0); STAGE(1, 1);
    VM4;                       // tile 0 landed; tile 1 (4 loads) in flight
    BAR; SB0;

    int b = 0, bs = 2;
    for (int t = 0; t < nt; ++t) {
        const u16* Lb = &Ld[b][0];
        bf16x8 fa[8], fb[4];
#pragma unroll
        for (int mi = 0; mi < 8; mi++)
            fa[mi] = *(const bf16x8*)&Lb[raw + (mi << 9) + phys];
#pragma unroll
        for (int ni = 0; ni < 4; ni++)
            fb[ni] = *(const bf16x8*)&Lb[rbw + (ni << 9) + phys];
        STAGE(t + 2, bs);
        BAR;
        __builtin_amdgcn_s_setprio(1);
#pragma unroll
        for (int mi = 0; mi < 8; mi++)
#pragma unroll
            for (int ni = 0; ni < 4; ni++)
                acc[mi][ni] = __builtin_amdgcn_mfma_f32_16x16x32_bf16(
                    fa[mi], fb[ni], acc[mi][ni], 0, 0, 0);
        __builtin_amdgcn_s_setprio(0);
        if (t + 2 < nt) { VM4; } else { VM0; }   // publish tile t+1
        BAR; SB0;
        b = (b == 2) ? 0 : b + 1;
        bs = (bs == 2) ? 0 : bs + 1;
    }
#undef STAGE

    const int colbase = n0 + (wc << 6) + (lane & 15);
    if (mode == 2) {
        float* C = (float*)Cout;
#pragma unroll
        for (int mi = 0; mi < 8; mi++)
#pragma unroll
            for (int r = 0; r < 4; r++) {
                int m = m0 + (wr << 7) + (mi << 4) + ((lane >> 4) << 2) + r;
                float* row = C + (size_t)m * N + colbase;
#pragma unroll
                for (int ni = 0; ni < 4; ni++) row[ni << 4] = acc[mi][ni][r];
            }
    } else if (n0 < 2048) {                   // fused QKV: RoPE region (Q and K)
        u16* C = (u16*)Cout;
#pragma unroll
        for (int mi = 0; mi < 8; mi++)
#pragma unroll
            for (int r = 0; r < 4; r++) {
                int m = m0 + (wr << 7) + (mi << 4) + ((lane >> 4) << 2) + r;
                const float* cb = cosp + ((size_t)m << 6);
                const float* sb = sinp + ((size_t)m << 6);
                u16* row = C + (size_t)m * N + colbase;
#pragma unroll
                for (int ni = 0; ni < 4; ni++) {
                    int d = (ni << 4) + (lane & 15);   // head-dim pos (0..63)
                    float c = cb[d], s = sb[d];
                    float v0 = acc[mi][ni][r];
                    float vr = acc[mi][ni ^ 2][r];     // d +/- 32 partner
                    float o = fmaf(v0, c, (ni < 2 ? -vr : vr) * s);
                    row[ni << 4] = bf16u(o);
                }
            }
    } else {                                  // V region: plain bf16
        u16* C = (u16*)Cout;
#pragma unroll
        for (int mi = 0; mi < 8; mi++)
#pragma unroll
            for (int r = 0; r < 4; r++) {
                int m = m0 + (wr << 7) + (mi << 4) + ((lane >> 4) << 2) + r;
                u16* row = C + (size_t)m * N + colbase;
#pragma unroll
                for (int ni = 0; ni < 4; ni++) row[ni << 4] = bf16u(acc[mi][ni][r]);
            }
    }
}

// ------- axial attention, both passes in one launch (4096 blocks) ----------
__global__ __launch_bounds__(256) void axial_attn(
    const u16* __restrict__ qkv, const float* __restrict__ mask,
    u16* __restrict__ cat)
{
    __shared__ u16 Kl[128 * 64];    // XOR-swizzled 16B chunks (^ row&7)
    __shared__ u16 VT[64 * 128];    // V^T, swizzled (^ d&15)
    __shared__ u16 Pl[128 * 128];   // P (q-major), swizzled (^ q&15)
    const int hmode = blockIdx.x >> 11;
    const int o2 = blockIdx.x & 2047;
    const int b = (o2 & 7) * 256 + (o2 >> 3);   // per-half XCD chunk swizzle
    const int a = b >> 4, hd = b & 15;
    const int tid = threadIdx.x, wid = tid >> 6, lane = tid & 63;
    const int tmul = hmode ? 128 : 1;
    const int tadd = hmode ? a : (a << 7);
    const size_t hoff = (size_t)hd << 6;

#pragma unroll
    for (int c = 0; c < 4; c++) {
        int row = (wid << 5) + (c << 3) + (lane >> 3);
        int sc = (lane & 7) ^ (row & 7);
        gl_lds16(qkv + (size_t)(row * tmul + tadd) * 3072 + 1024 + hoff + (sc << 3),
                 &Kl[((wid << 5) + (c << 3)) << 6]);
    }
#pragma unroll
    for (int i = 0; i < 4; i++) {
        int cid = tid + (i << 8);
        int j = cid >> 3;
        int d0 = (cid & 7) << 3;
        uint4 raw = *(const uint4*)(qkv + (size_t)(j * tmul + tadd) * 3072 + 2048 + hoff + d0);
        const u16* e = (const u16*)&raw;
#pragma unroll
        for (int t = 0; t < 8; t++) {
            int d = d0 + t;
            VT[(d << 7) + (((j >> 3) ^ (d & 15)) << 3) + (j & 7)] = e[t];
        }
    }
    bf16x8 aq[2][2];
#pragma unroll
    for (int qt = 0; qt < 2; qt++)
#pragma unroll
        for (int ks = 0; ks < 2; ks++) {
            int row = (wid << 5) + (qt << 4) + (lane & 15);
            aq[qt][ks] = *(const bf16x8*)(qkv + (size_t)(row * tmul + tadd) * 3072 + hoff
                                          + (ks << 5) + ((lane >> 4) << 3));
        }
    __syncthreads();

    f32x4 S[2][8] = {};
#pragma unroll
    for (int kt = 0; kt < 8; kt++) {
        bf16x8 bk[2];
#pragma unroll
        for (int ks = 0; ks < 2; ks++) {
            int row = (kt << 4) + (lane & 15);
            int ch = ((ks << 2) + (lane >> 4)) ^ (row & 7);
            bk[ks] = *(const bf16x8*)&Kl[(row << 6) + (ch << 3)];
        }
#pragma unroll
        for (int qt = 0; qt < 2; qt++) {
            S[qt][kt] = __builtin_amdgcn_mfma_f32_16x16x32_bf16(aq[qt][0], bk[0], S[qt][kt], 0, 0, 0);
            S[qt][kt] = __builtin_amdgcn_mfma_f32_16x16x32_bf16(aq[qt][1], bk[1], S[qt][kt], 0, 0, 0);
        }
    }

    const float scale = 0.03125f;   // 1/sqrt(1024)
#pragma unroll
    for (int qt = 0; qt < 2; qt++) {
#pragma unroll
        for (int r = 0; r < 4; r++) {
            int qrow = (wid << 5) + (qt << 4) + ((lane >> 4) << 2) + r;
            const float* mrow = mask + (hmode ? (a << 7) : (qrow << 7));
            float mx = -1e30f;
#pragma unroll
            for (int kt = 0; kt < 8; kt++) {
                float sv = fmaf(S[qt][kt][r], scale, mrow[(kt << 4) + (lane & 15)]);
                S[qt][kt][r] = sv;
                mx = fmaxf(mx, sv);
            }
            mx = fmaxf(mx, __shfl_xor(mx, 1));
            mx = fmaxf(mx, __shfl_xor(mx, 2));
            mx = fmaxf(mx, __shfl_xor(mx, 4));
            mx = fmaxf(mx, __shfl_xor(mx, 8));
            float sum = 0.f;
#pragma unroll
            for (int kt = 0; kt < 8; kt++) {
                float p = __expf(S[qt][kt][r] - mx);
                S[qt][kt][r] = p;
                sum += p;
            }
            sum += __shfl_xor(sum, 1);
            sum += __shfl_xor(sum, 2);
            sum += __shfl_xor(sum, 4);
            sum += __shfl_xor(sum, 8);
            float rinv = 1.0f / sum;
#pragma unroll
            for (int kt = 0; kt < 8; kt++) {
                int kcol = (kt << 4) + (lane & 15);
                int ch = (kcol >> 3) ^ (qrow & 15);
                Pl[(qrow << 7) + (ch << 3) + (kcol & 7)] = bf16u(S[qt][kt][r] * rinv);
            }
        }
    }
    __syncthreads();

    f32x4 O[4][2] = {};
#pragma unroll
    for (int ks = 0; ks < 4; ks++) {
        bf16x8 av[4], bp[2];
#pragma unroll
        for (int dt = 0; dt < 4; dt++) {
            int drow = (dt << 4) + (lane & 15);
            int ch = ((ks << 2) + (lane >> 4)) ^ (drow & 15);
            av[dt] = *(const bf16x8*)&VT[(drow << 7) + (ch << 3)];
        }
#pragma unroll
        for (int qt = 0; qt < 2; qt++) {
            int qrow = (wid << 5) + (qt << 4) + (lane & 15);
            int ch = ((ks << 2) + (lane >> 4)) ^ (qrow & 15);
            bp[qt] = *(const bf16x8*)&Pl[(qrow << 7) + (ch << 3)];
        }
#pragma unroll
        for (int dt = 0; dt < 4; dt++)
#pragma unroll
            for (int qt = 0; qt < 2; qt++)
                O[dt][qt] = __builtin_amdgcn_mfma_f32_16x16x32_bf16(av[dt], bp[qt], O[dt][qt], 0, 0, 0);
    }

    const int cbase = (hmode ? 1024 : 0) + (hd << 6);
#pragma unroll
    for (int dt = 0; dt < 4; dt++)
#pragma unroll
        for (int qt = 0; qt < 2; qt++) {
            int qrow = (wid << 5) + (qt << 4) + (lane & 15);
            int d0 = (dt << 4) + ((lane >> 4) << 2);
            size_t base = ((size_t)(qrow * tmul + tadd) << 11) + cbase + d0;
            ushort4 pk;
            pk.x = bf16u(O[dt][qt][0]);
            pk.y = bf16u(O[dt][qt][1]);
            pk.z = bf16u(O[dt][qt][2]);
            pk.w = bf16u(O[dt][qt][3]);
            *(ushort4*)(cat + base) = pk;
        }
}

extern "C" void kernel_launch(void* const* d_in, const int* in_sizes, int n_in,
                              void* d_out, int out_size, void* d_ws, size_t ws_size,
                              hipStream_t stream)
{
    (void)in_sizes; (void)n_in; (void)out_size; (void)ws_size;
    const float* hidden = (const float*)d_in[0];
    const float* mask   = (const float*)d_in[1];
    const float* cosp   = (const float*)d_in[2];
    const float* sinp   = (const float*)d_in[3];
    const float* Wq     = (const float*)d_in[4];
    const float* Wk     = (const float*)d_in[5];
    const float* Wv     = (const float*)d_in[6];
    const float* Wo     = (const float*)d_in[7];

    char* ws = (char*)d_ws;
    u16* Xb    = (u16*)(ws);                  // 33,554,432 B
    u16* WqkvT = (u16*)(ws + 33554432);       //  6,291,456 B
    u16* cat   = (u16*)(ws);                  // 67,108,864 B (reuse, stream-ordered)
    u16* WoT   = (u16*)(ws + 67108864);       //  4,194,304 B
    u16* qkvb  = (u16*)(ws + 71303168);       // 100,663,296 B

    prep_all<<<dim3(32, 64, 5), 256, 0, stream>>>(hidden, (ushort4*)Xb,
                                                  Wq, Wk, Wv, Wo, WqkvT, WoT);

    // fused QKV projection + RoPE: [16384,1024] x [1024,3072]  (pair-step, r11)
    gemm_pp<<<dim3(24, 128), 256, 0, stream>>>(Xb, WqkvT, qkvb, cosp, sinp, 16384, 3072, 1024, 1);

    axial_attn<<<4096, 256, 0, stream>>>(qkvb, mask, cat);

    // output projection: [16384,2048] x [2048,1024] -> fp32  (fat-phase 256², r7)
    gemm_fat<<<dim3(4, 64), 512, 0, stream>>>(cat, WoT, d_out, nullptr, nullptr, 16384, 1024, 2048, 2);
}

// Round 14
// 318.356 us; speedup vs baseline: 1.5600x; 1.0139x over previous
//
#include <hip/hip_runtime.h>

typedef unsigned short u16;
typedef unsigned int   u32;
typedef __bf16 bf16;
typedef bf16  bf16x8 __attribute__((ext_vector_type(8)));
typedef float f32x4  __attribute__((ext_vector_type(4)));

__device__ __forceinline__ u16 bf16u(float f) {
    u32 x = __builtin_bit_cast(u32, f);
    x += 0x7fffu + ((x >> 16) & 1u);   // RNE
    return (u16)(x >> 16);
}

__device__ __forceinline__ void gl_lds16(const void* g, void* l) {
    __builtin_amdgcn_global_load_lds(
        (const __attribute__((address_space(1))) u32*)g,
        (__attribute__((address_space(3))) u32*)l, 16, 0, 0);
}

// ---- merged prep: fp32->bf16 convert (z==4) + 4 weight transposes (z<4) ----
__global__ __launch_bounds__(256) void prep_all(
    const float* __restrict__ hidden, ushort4* __restrict__ Xb,
    const float* __restrict__ Wq, const float* __restrict__ Wk,
    const float* __restrict__ Wv, const float* __restrict__ Wo,
    u16* __restrict__ WqkvT, u16* __restrict__ WoT)
{
    const int z = blockIdx.z;
    if (z == 4) {   // cvt: 2048 blocks x 8 float4-chunks of 256
        const float4* in = (const float4*)hidden;
        int b = blockIdx.y * 32 + blockIdx.x;
#pragma unroll
        for (int it = 0; it < 8; it++) {
            int i = (b << 11) + (it << 8) + threadIdx.x;
            float4 f = in[i];
            ushort4 o;
            o.x = bf16u(f.x); o.y = bf16u(f.y); o.z = bf16u(f.z); o.w = bf16u(f.w);
            Xb[i] = o;
        }
        return;
    }
    const float* W; u16* WT; int rows, cols;
    if (z < 3) {
        if (blockIdx.y >= 32) return;
        W = (z == 0) ? Wq : (z == 1) ? Wk : Wv;
        WT = WqkvT + (size_t)z * 1024 * 1024;
        rows = 1024; cols = 1024;
    } else {
        W = Wo; WT = WoT; rows = 2048; cols = 1024;
    }
    __shared__ float t[32][33];
    int bx = blockIdx.x * 32, by = blockIdx.y * 32;
    int x = threadIdx.x & 31, y = threadIdx.x >> 5;
#pragma unroll
    for (int i = 0; i < 32; i += 8)
        t[y + i][x] = W[(size_t)(by + y + i) * cols + bx + x];
    __syncthreads();
#pragma unroll
    for (int i = 0; i < 32; i += 8)
        WT[(size_t)(bx + y + i) * rows + by + x] = bf16u(t[x][y + i]);
}

#define BAR   __builtin_amdgcn_s_barrier()
#define SB0   __builtin_amdgcn_sched_barrier(0)
#define VM4   asm volatile("s_waitcnt vmcnt(4)" ::: "memory")
#define VM0   asm volatile("s_waitcnt vmcnt(0)" ::: "memory")

// ====== 256x256 GEMM, fat-phase 3-buffer, READ-ORDER-FIXED ======
// 512 thr = 8 waves (2M x 4N), wave 128x64; BK=32; 96 KB LDS; 2 blocks/CU.
// Phase t: {4 B-frag reads, then 8 A-frag reads | stage t+2} BAR; 32 MFMA
// (mi-outer: group mi gated by reads 1..5+mi only -> compiler's progressive
// lgkmcnt starts MFMAs at ~5/12 of the read burst, hiding the tail under
// MFMA); publish t+1 via counted vmcnt; BAR; SB0.
// KEY CHANGE vs r7/r13: fb read BEFORE fa. Previously first MFMA needed read
// #9/12 -> full read-burst drain before any MFMA -> measured 1940cy/phase
// (28% MfmaUtil). Same addresses/barriers/swizzle: zero correctness delta.
// Chunk swizzle (verified 0-conflict): LDS slot s at row r holds global
// k-chunk s^((r>>1)&3); inverse on gl_lds SOURCE, forward on ds_read.
// mode 1: bf16 out + fused RoPE when col<2048.  mode 2: fp32 out.
__global__ __launch_bounds__(512, 2) void gemm_fat(
    const u16* __restrict__ A, const u16* __restrict__ BT, void* __restrict__ Cout,
    const float* __restrict__ cosp, const float* __restrict__ sinp,
    int M, int N, int K, int mode)
{
    __shared__ u16 Ld[3][16384];   // per buf: A @0 (8192 u16), B @8192
    const int tid = threadIdx.x;
    const int wid = tid >> 6, lane = tid & 63;
    const int nx = gridDim.x;
    const int nwg = nx * gridDim.y;
    const int orig = blockIdx.y * nx + blockIdx.x;
    const int vid = (orig & 7) * (nwg >> 3) + (orig >> 3);
    const int m0 = (vid / nx) << 8, n0 = (vid % nx) << 8;
    const int wr = wid >> 2, wc = wid & 3;

    const int srow = tid >> 2;                     // row 0..127
    const int sl = (tid & 3) ^ ((srow >> 1) & 3);  // inverse-swizzled chunk
    const u16* aS0 = A + (size_t)(m0 + srow) * K + (sl << 3);
    const u16* aS1 = aS0 + (size_t)128 * K;
    const u16* bS0 = BT + (size_t)(n0 + srow) * K + (sl << 3);
    const u16* bS1 = bS0 + (size_t)128 * K;
    const int wdb = wid << 9;                      // wave-uniform dest (u16)
    const int nt = K >> 5;

#define STAGE(T, B_) do { if ((T) < nt) { size_t _ko = (size_t)(T) << 5; \
        gl_lds16(aS0 + _ko, &Ld[B_][wdb]); \
        gl_lds16(aS1 + _ko, &Ld[B_][4096 + wdb]); \
        gl_lds16(bS0 + _ko, &Ld[B_][8192 + wdb]); \
        gl_lds16(bS1 + _ko, &Ld[B_][12288 + wdb]); } } while (0)

    const int phys = ((lane >> 4) ^ ((lane >> 1) & 3)) << 3;   // u16 offset
    const int raw = ((wr << 7) + (lane & 15)) << 5;            // A row base (u16)
    const int rbw = (((wc << 6) + (lane & 15)) << 5) + 8192;   // B row base (u16)

    f32x4 acc[8][4] = {};

    STAGE(0, 0); STAGE(1, 1);
    VM4;                       // tile 0 landed; tile 1 (4 loads) in flight
    BAR; SB0;

    int b = 0, bs = 2;
    for (int t = 0; t < nt; ++t) {
        const u16* Lb = &Ld[b][0];
        bf16x8 fa[8], fb[4];
        // ---- B-frags FIRST (reads 1-4), then A-frags (reads 5-12) ----
#pragma unroll
        for (int ni = 0; ni < 4; ni++)
            fb[ni] = *(const bf16x8*)&Lb[rbw + (ni << 9) + phys];
#pragma unroll
        for (int mi = 0; mi < 8; mi++)
            fa[mi] = *(const bf16x8*)&Lb[raw + (mi << 9) + phys];
        STAGE(t + 2, bs);
        BAR;
        __builtin_amdgcn_s_setprio(1);
        // mi-outer: MFMA group mi gated by fb[0..3] + fa[mi] = reads 1..5+mi
#pragma unroll
        for (int mi = 0; mi < 8; mi++)
#pragma unroll
            for (int ni = 0; ni < 4; ni++)
                acc[mi][ni] = __builtin_amdgcn_mfma_f32_16x16x32_bf16(
                    fa[mi], fb[ni], acc[mi][ni], 0, 0, 0);
        __builtin_amdgcn_s_setprio(0);
        if (t + 2 < nt) { VM4; } else { VM0; }   // publish tile t+1
        BAR; SB0;
        b = (b == 2) ? 0 : b + 1;
        bs = (bs == 2) ? 0 : bs + 1;
    }
#undef STAGE

    const int colbase = n0 + (wc << 6) + (lane & 15);
    if (mode == 2) {
        float* C = (float*)Cout;
#pragma unroll
        for (int mi = 0; mi < 8; mi++)
#pragma unroll
            for (int r = 0; r < 4; r++) {
                int m = m0 + (wr << 7) + (mi << 4) + ((lane >> 4) << 2) + r;
                float* row = C + (size_t)m * N + colbase;
#pragma unroll
                for (int ni = 0; ni < 4; ni++) row[ni << 4] = acc[mi][ni][r];
            }
    } else if (n0 < 2048) {                   // fused QKV: RoPE region (Q and K)
        u16* C = (u16*)Cout;
#pragma unroll
        for (int mi = 0; mi < 8; mi++)
#pragma unroll
            for (int r = 0; r < 4; r++) {
                int m = m0 + (wr << 7) + (mi << 4) + ((lane >> 4) << 2) + r;
                const float* cb = cosp + ((size_t)m << 6);
                const float* sb = sinp + ((size_t)m << 6);
                u16* row = C + (size_t)m * N + colbase;
#pragma unroll
                for (int ni = 0; ni < 4; ni++) {
                    int d = (ni << 4) + (lane & 15);   // head-dim pos (0..63)
                    float c = cb[d], s = sb[d];
                    float v0 = acc[mi][ni][r];
                    float vr = acc[mi][ni ^ 2][r];     // d +/- 32 partner
                    float o = fmaf(v0, c, (ni < 2 ? -vr : vr) * s);
                    row[ni << 4] = bf16u(o);
                }
            }
    } else {                                  // V region: plain bf16
        u16* C = (u16*)Cout;
#pragma unroll
        for (int mi = 0; mi < 8; mi++)
#pragma unroll
            for (int r = 0; r < 4; r++) {
                int m = m0 + (wr << 7) + (mi << 4) + ((lane >> 4) << 2) + r;
                u16* row = C + (size_t)m * N + colbase;
#pragma unroll
                for (int ni = 0; ni < 4; ni++) row[ni << 4] = bf16u(acc[mi][ni][r]);
            }
    }
}

// ------- axial attention, both passes in one launch (4096 blocks) ----------
__global__ __launch_bounds__(256) void axial_attn(
    const u16* __restrict__ qkv, const float* __restrict__ mask,
    u16* __restrict__ cat)
{
    __shared__ u16 Kl[128 * 64];    // XOR-swizzled 16B chunks (^ row&7)
    __shared__ u16 VT[64 * 128];    // V^T, swizzled (^ d&15)
    __shared__ u16 Pl[128 * 128];   // P (q-major), swizzled (^ q&15)
    const int hmode = blockIdx.x >> 11;
    const int o2 = blockIdx.x & 2047;
    const int b = (o2 & 7) * 256 + (o2 >> 3);   // per-half XCD chunk swizzle
    const int a = b >> 4, hd = b & 15;
    const int tid = threadIdx.x, wid = tid >> 6, lane = tid & 63;
    const int tmul = hmode ? 128 : 1;
    const int tadd = hmode ? a : (a << 7);
    const size_t hoff = (size_t)hd << 6;

#pragma unroll
    for (int c = 0; c < 4; c++) {
        int row = (wid << 5) + (c << 3) + (lane >> 3);
        int sc = (lane & 7) ^ (row & 7);
        gl_lds16(qkv + (size_t)(row * tmul + tadd) * 3072 + 1024 + hoff + (sc << 3),
                 &Kl[((wid << 5) + (c << 3)) << 6]);
    }
#pragma unroll
    for (int i = 0; i < 4; i++) {
        int cid = tid + (i << 8);
        int j = cid >> 3;
        int d0 = (cid & 7) << 3;
        uint4 raw = *(const uint4*)(qkv + (size_t)(j * tmul + tadd) * 3072 + 2048 + hoff + d0);
        const u16* e = (const u16*)&raw;
#pragma unroll
        for (int t = 0; t < 8; t++) {
            int d = d0 + t;
            VT[(d << 7) + (((j >> 3) ^ (d & 15)) << 3) + (j & 7)] = e[t];
        }
    }
    bf16x8 aq[2][2];
#pragma unroll
    for (int qt = 0; qt < 2; qt++)
#pragma unroll
        for (int ks = 0; ks < 2; ks++) {
            int row = (wid << 5) + (qt << 4) + (lane & 15);
            aq[qt][ks] = *(const bf16x8*)(qkv + (size_t)(row * tmul + tadd) * 3072 + hoff
                                          + (ks << 5) + ((lane >> 4) << 3));
        }
    __syncthreads();

    f32x4 S[2][8] = {};
#pragma unroll
    for (int kt = 0; kt < 8; kt++) {
        bf16x8 bk[2];
#pragma unroll
        for (int ks = 0; ks < 2; ks++) {
            int row = (kt << 4) + (lane & 15);
            int ch = ((ks << 2) + (lane >> 4)) ^ (row & 7);
            bk[ks] = *(const bf16x8*)&Kl[(row << 6) + (ch << 3)];
        }
#pragma unroll
        for (int qt = 0; qt < 2; qt++) {
            S[qt][kt] = __builtin_amdgcn_mfma_f32_16x16x32_bf16(aq[qt][0], bk[0], S[qt][kt], 0, 0, 0);
            S[qt][kt] = __builtin_amdgcn_mfma_f32_16x16x32_bf16(aq[qt][1], bk[1], S[qt][kt], 0, 0, 0);
        }
    }

    const float scale = 0.03125f;   // 1/sqrt(1024)
#pragma unroll
    for (int qt = 0; qt < 2; qt++) {
#pragma unroll
        for (int r = 0; r < 4; r++) {
            int qrow = (wid << 5) + (qt << 4) + ((lane >> 4) << 2) + r;
            const float* mrow = mask + (hmode ? (a << 7) : (qrow << 7));
            float mx = -1e30f;
#pragma unroll
            for (int kt = 0; kt < 8; kt++) {
                float sv = fmaf(S[qt][kt][r], scale, mrow[(kt << 4) + (lane & 15)]);
                S[qt][kt][r] = sv;
                mx = fmaxf(mx, sv);
            }
            mx = fmaxf(mx, __shfl_xor(mx, 1));
            mx = fmaxf(mx, __shfl_xor(mx, 2));
            mx = fmaxf(mx, __shfl_xor(mx, 4));
            mx = fmaxf(mx, __shfl_xor(mx, 8));
            float sum = 0.f;
#pragma unroll
            for (int kt = 0; kt < 8; kt++) {
                float p = __expf(S[qt][kt][r] - mx);
                S[qt][kt][r] = p;
                sum += p;
            }
            sum += __shfl_xor(sum, 1);
            sum += __shfl_xor(sum, 2);
            sum += __shfl_xor(sum, 4);
            sum += __shfl_xor(sum, 8);
            float rinv = 1.0f / sum;
#pragma unroll
            for (int kt = 0; kt < 8; kt++) {
                int kcol = (kt << 4) + (lane & 15);
                int ch = (kcol >> 3) ^ (qrow & 15);
                Pl[(qrow << 7) + (ch << 3) + (kcol & 7)] = bf16u(S[qt][kt][r] * rinv);
            }
        }
    }
    __syncthreads();

    f32x4 O[4][2] = {};
#pragma unroll
    for (int ks = 0; ks < 4; ks++) {
        bf16x8 av[4], bp[2];
#pragma unroll
        for (int qt = 0; qt < 2; qt++) {
            int qrow = (wid << 5) + (qt << 4) + (lane & 15);
            int ch = ((ks << 2) + (lane >> 4)) ^ (qrow & 15);
            bp[qt] = *(const bf16x8*)&Pl[(qrow << 7) + (ch << 3)];
        }
#pragma unroll
        for (int dt = 0; dt < 4; dt++) {
            int drow = (dt << 4) + (lane & 15);
            int ch = ((ks << 2) + (lane >> 4)) ^ (drow & 15);
            av[dt] = *(const bf16x8*)&VT[(drow << 7) + (ch << 3)];
        }
#pragma unroll
        for (int dt = 0; dt < 4; dt++)
#pragma unroll
            for (int qt = 0; qt < 2; qt++)
                O[dt][qt] = __builtin_amdgcn_mfma_f32_16x16x32_bf16(av[dt], bp[qt], O[dt][qt], 0, 0, 0);
    }

    const int cbase = (hmode ? 1024 : 0) + (hd << 6);
#pragma unroll
    for (int dt = 0; dt < 4; dt++)
#pragma unroll
        for (int qt = 0; qt < 2; qt++) {
            int qrow = (wid << 5) + (qt << 4) + (lane & 15);
            int d0 = (dt << 4) + ((lane >> 4) << 2);
            size_t base = ((size_t)(qrow * tmul + tadd) << 11) + cbase + d0;
            ushort4 pk;
            pk.x = bf16u(O[dt][qt][0]);
            pk.y = bf16u(O[dt][qt][1]);
            pk.z = bf16u(O[dt][qt][2]);
            pk.w = bf16u(O[dt][qt][3]);
            *(ushort4*)(cat + base) = pk;
        }
}

extern "C" void kernel_launch(void* const* d_in, const int* in_sizes, int n_in,
                              void* d_out, int out_size, void* d_ws, size_t ws_size,
                              hipStream_t stream)
{
    (void)in_sizes; (void)n_in; (void)out_size; (void)ws_size;
    const float* hidden = (const float*)d_in[0];
    const float* mask   = (const float*)d_in[1];
    const float* cosp   = (const float*)d_in[2];
    const float* sinp   = (const float*)d_in[3];
    const float* Wq     = (const float*)d_in[4];
    const float* Wk     = (const float*)d_in[5];
    const float* Wv     = (const float*)d_in[6];
    const float* Wo     = (const float*)d_in[7];

    char* ws = (char*)d_ws;
    u16* Xb    = (u16*)(ws);                  // 33,554,432 B
    u16* WqkvT = (u16*)(ws + 33554432);       //  6,291,456 B
    u16* cat   = (u16*)(ws);                  // 67,108,864 B (reuse, stream-ordered)
    u16* WoT   = (u16*)(ws + 67108864);       //  4,194,304 B
    u16* qkvb  = (u16*)(ws + 71303168);       // 100,663,296 B

    prep_all<<<dim3(32, 64, 5), 256, 0, stream>>>(hidden, (ushort4*)Xb,
                                                  Wq, Wk, Wv, Wo, WqkvT, WoT);

    // fused QKV projection + RoPE: [16384,1024] x [1024,3072]
    gemm_fat<<<dim3(12, 64), 512, 0, stream>>>(Xb, WqkvT, qkvb, cosp, sinp, 16384, 3072, 1024, 1);

    axial_attn<<<4096, 256, 0, stream>>>(qkvb, mask, cat);

    // output projection: [16384,2048] x [2048,1024] -> fp32
    gemm_fat<<<dim3(4, 64), 512, 0, stream>>>(cat, WoT, d_out, nullptr, nullptr, 16384, 1024, 2048, 2);
}

// Round 15
// 312.876 us; speedup vs baseline: 1.5873x; 1.0175x over previous
//
#include <hip/hip_runtime.h>

typedef unsigned short u16;
typedef unsigned int   u32;
typedef __bf16 bf16;
typedef bf16  bf16x8 __attribute__((ext_vector_type(8)));
typedef float f32x4  __attribute__((ext_vector_type(4)));

__device__ __forceinline__ u16 bf16u(float f) {
    u32 x = __builtin_bit_cast(u32, f);
    x += 0x7fffu + ((x >> 16) & 1u);   // RNE
    return (u16)(x >> 16);
}

__device__ __forceinline__ void gl_lds16(const void* g, void* l) {
    __builtin_amdgcn_global_load_lds(
        (const __attribute__((address_space(1))) u32*)g,
        (__attribute__((address_space(3))) u32*)l, 16, 0, 0);
}

// ---- merged prep: fp32->bf16 convert (z==4) + 4 weight transposes (z<4) ----
__global__ __launch_bounds__(256) void prep_all(
    const float* __restrict__ hidden, ushort4* __restrict__ Xb,
    const float* __restrict__ Wq, const float* __restrict__ Wk,
    const float* __restrict__ Wv, const float* __restrict__ Wo,
    u16* __restrict__ WqkvT, u16* __restrict__ WoT)
{
    const int z = blockIdx.z;
    if (z == 4) {   // cvt: 2048 blocks x 8 float4-chunks of 256
        const float4* in = (const float4*)hidden;
        int b = blockIdx.y * 32 + blockIdx.x;
#pragma unroll
        for (int it = 0; it < 8; it++) {
            int i = (b << 11) + (it << 8) + threadIdx.x;
            float4 f = in[i];
            ushort4 o;
            o.x = bf16u(f.x); o.y = bf16u(f.y); o.z = bf16u(f.z); o.w = bf16u(f.w);
            Xb[i] = o;
        }
        return;
    }
    const float* W; u16* WT; int rows, cols;
    if (z < 3) {
        if (blockIdx.y >= 32) return;
        W = (z == 0) ? Wq : (z == 1) ? Wk : Wv;
        WT = WqkvT + (size_t)z * 1024 * 1024;
        rows = 1024; cols = 1024;
    } else {
        W = Wo; WT = WoT; rows = 2048; cols = 1024;
    }
    __shared__ float t[32][33];
    int bx = blockIdx.x * 32, by = blockIdx.y * 32;
    int x = threadIdx.x & 31, y = threadIdx.x >> 5;
#pragma unroll
    for (int i = 0; i < 32; i += 8)
        t[y + i][x] = W[(size_t)(by + y + i) * cols + bx + x];
    __syncthreads();
#pragma unroll
    for (int i = 0; i < 32; i += 8)
        WT[(size_t)(bx + y + i) * rows + by + x] = bf16u(t[x][y + i]);
}

#define BAR   __builtin_amdgcn_s_barrier()
#define SB0   __builtin_amdgcn_sched_barrier(0)
#define VM4   asm volatile("s_waitcnt vmcnt(4)" ::: "memory")
#define VM0   asm volatile("s_waitcnt vmcnt(0)" ::: "memory")

// ====== 128x128 GEMM, pair-step (r11/r13, measured 151.4us QKV) ======
// 4x16KB bufs, barrier-pair per 2 K-steps, 2 blocks/CU; grid 3072 blocks =
// 6.0 exact co-residency rounds (no tail). B-frags read first (r14 tweak).
__global__ __launch_bounds__(256, 2) void gemm_pp(
    const u16* __restrict__ A, const u16* __restrict__ BT, void* __restrict__ Cout,
    const float* __restrict__ cosp, const float* __restrict__ sinp,
    int M, int N, int K, int mode)
{
    __shared__ u16 Ld[4][8192];    // per buf: A @0 (4096 u16), B @4096 = 16 KB
    const int tid = threadIdx.x;
    const int wid = tid >> 6, lane = tid & 63;
    const int nx = gridDim.x;
    const int nwg = nx * gridDim.y;
    const int orig = blockIdx.y * nx + blockIdx.x;
    const int vid = (orig & 7) * (nwg >> 3) + (orig >> 3);
    const int m0 = (vid / nx) << 7, n0 = (vid % nx) << 7;
    const int wr = wid >> 1, wc = wid & 1;

    const int srow = tid >> 2;                       // 0..63
    const int sg = (tid & 3) ^ ((srow >> 1) & 3);    // inverse-swizzled k-chunk
    const u16* aS = A + (size_t)(m0 + srow) * K + (sg << 3);
    const u16* bS = BT + (size_t)(n0 + srow) * K + (sg << 3);
    const size_t h64K = (size_t)64 * K;
    const int wdb = wid << 9;                        // wave-uniform dest (u16)
    const int nt = K >> 5;                           // even

#define STAGE(T) do { const int _b = (T) & 3; const size_t _ko = (size_t)(T) << 5; \
        gl_lds16(aS + _ko,        &Ld[_b][wdb]); \
        gl_lds16(aS + _ko + h64K, &Ld[_b][2048 + wdb]); \
        gl_lds16(bS + _ko,        &Ld[_b][4096 + wdb]); \
        gl_lds16(bS + _ko + h64K, &Ld[_b][6144 + wdb]); } while (0)

    const int phys = ((lane >> 4) ^ ((lane >> 1) & 3)) << 3;
    const int raw = ((wr << 6) + (lane & 15)) << 5;          // A row base (u16)
    const int rbw = (((wc << 6) + (lane & 15)) << 5) + 4096; // B row base (u16)

    f32x4 acc[4][4] = {};

    STAGE(0); STAGE(1);
    VM0; BAR;

    for (int t = 0; t < nt; t += 2) {
        if (t + 2 < nt) STAGE(t + 2);
        if (t + 3 < nt) STAGE(t + 3);
        {   // ---- K-step t ----
            const u16* Lb = &Ld[t & 3][0];
            bf16x8 af[4], bfr[4];
#pragma unroll
            for (int i = 0; i < 4; i++)
                bfr[i] = *(const bf16x8*)&Lb[rbw + (i << 9) + phys];
#pragma unroll
            for (int i = 0; i < 4; i++)
                af[i] = *(const bf16x8*)&Lb[raw + (i << 9) + phys];
            __builtin_amdgcn_s_setprio(1);
#pragma unroll
            for (int mi = 0; mi < 4; mi++)
#pragma unroll
                for (int ni = 0; ni < 4; ni++)
                    acc[mi][ni] = __builtin_amdgcn_mfma_f32_16x16x32_bf16(
                        af[mi], bfr[ni], acc[mi][ni], 0, 0, 0);
            __builtin_amdgcn_s_setprio(0);
        }
        {   // ---- K-step t+1 (buffer pre-published; reads overlap above MFMA) ----
            const u16* Lb = &Ld[(t + 1) & 3][0];
            bf16x8 af[4], bfr[4];
#pragma unroll
            for (int i = 0; i < 4; i++)
                bfr[i] = *(const bf16x8*)&Lb[rbw + (i << 9) + phys];
#pragma unroll
            for (int i = 0; i < 4; i++)
                af[i] = *(const bf16x8*)&Lb[raw + (i << 9) + phys];
            __builtin_amdgcn_s_setprio(1);
#pragma unroll
            for (int mi = 0; mi < 4; mi++)
#pragma unroll
                for (int ni = 0; ni < 4; ni++)
                    acc[mi][ni] = __builtin_amdgcn_mfma_f32_16x16x32_bf16(
                        af[mi], bfr[ni], acc[mi][ni], 0, 0, 0);
            __builtin_amdgcn_s_setprio(0);
        }
        VM0; BAR;
    }
#undef STAGE

    const int colbase = n0 + (wc << 6) + (lane & 15);
    if (mode == 2) {
        float* C = (float*)Cout;
#pragma unroll
        for (int mi = 0; mi < 4; mi++)
#pragma unroll
            for (int r = 0; r < 4; r++) {
                int m = m0 + (wr << 6) + (mi << 4) + ((lane >> 4) << 2) + r;
                float* row = C + (size_t)m * N + colbase;
#pragma unroll
                for (int ni = 0; ni < 4; ni++) row[ni << 4] = acc[mi][ni][r];
            }
    } else if (n0 < 2048) {                   // fused QKV: RoPE region (Q and K)
        u16* C = (u16*)Cout;
#pragma unroll
        for (int mi = 0; mi < 4; mi++)
#pragma unroll
            for (int r = 0; r < 4; r++) {
                int m = m0 + (wr << 6) + (mi << 4) + ((lane >> 4) << 2) + r;
                const float* cb = cosp + ((size_t)m << 6);
                const float* sb = sinp + ((size_t)m << 6);
                u16* row = C + (size_t)m * N + colbase;
#pragma unroll
                for (int ni = 0; ni < 4; ni++) {
                    int d = (ni << 4) + (lane & 15);   // head-dim pos (0..63)
                    float c = cb[d], s = sb[d];
                    float v0 = acc[mi][ni][r];
                    float vr = acc[mi][ni ^ 2][r];     // d +/- 32 partner
                    float o = fmaf(v0, c, (ni < 2 ? -vr : vr) * s);
                    row[ni << 4] = bf16u(o);
                }
            }
    } else {                                  // V region: plain bf16
        u16* C = (u16*)Cout;
#pragma unroll
        for (int mi = 0; mi < 4; mi++)
#pragma unroll
            for (int r = 0; r < 4; r++) {
                int m = m0 + (wr << 6) + (mi << 4) + ((lane >> 4) << 2) + r;
                u16* row = C + (size_t)m * N + colbase;
#pragma unroll
                for (int ni = 0; ni < 4; ni++) row[ni << 4] = bf16u(acc[mi][ni][r]);
            }
    }
}

// ====== 256x256 GEMM, fat-phase 3-buffer, read-order-fixed (r14 Wo) ======
__global__ __launch_bounds__(512, 2) void gemm_fat(
    const u16* __restrict__ A, const u16* __restrict__ BT, void* __restrict__ Cout,
    const float* __restrict__ cosp, const float* __restrict__ sinp,
    int M, int N, int K, int mode)
{
    __shared__ u16 Ld[3][16384];   // per buf: A @0 (8192 u16), B @8192
    const int tid = threadIdx.x;
    const int wid = tid >> 6, lane = tid & 63;
    const int nx = gridDim.x;
    const int nwg = nx * gridDim.y;
    const int orig = blockIdx.y * nx + blockIdx.x;
    const int vid = (orig & 7) * (nwg >> 3) + (orig >> 3);
    const int m0 = (vid / nx) << 8, n0 = (vid % nx) << 8;
    const int wr = wid >> 2, wc = wid & 3;

    const int srow = tid >> 2;                     // row 0..127
    const int sl = (tid & 3) ^ ((srow >> 1) & 3);  // inverse-swizzled chunk
    const u16* aS0 = A + (size_t)(m0 + srow) * K + (sl << 3);
    const u16* aS1 = aS0 + (size_t)128 * K;
    const u16* bS0 = BT + (size_t)(n0 + srow) * K + (sl << 3);
    const u16* bS1 = bS0 + (size_t)128 * K;
    const int wdb = wid << 9;                      // wave-uniform dest (u16)
    const int nt = K >> 5;

#define STAGE(T, B_) do { if ((T) < nt) { size_t _ko = (size_t)(T) << 5; \
        gl_lds16(aS0 + _ko, &Ld[B_][wdb]); \
        gl_lds16(aS1 + _ko, &Ld[B_][4096 + wdb]); \
        gl_lds16(bS0 + _ko, &Ld[B_][8192 + wdb]); \
        gl_lds16(bS1 + _ko, &Ld[B_][12288 + wdb]); } } while (0)

    const int phys = ((lane >> 4) ^ ((lane >> 1) & 3)) << 3;   // u16 offset
    const int raw = ((wr << 7) + (lane & 15)) << 5;            // A row base (u16)
    const int rbw = (((wc << 6) + (lane & 15)) << 5) + 8192;   // B row base (u16)

    f32x4 acc[8][4] = {};

    STAGE(0, 0); STAGE(1, 1);
    VM4;                       // tile 0 landed; tile 1 (4 loads) in flight
    BAR; SB0;

    int b = 0, bs = 2;
    for (int t = 0; t < nt; ++t) {
        const u16* Lb = &Ld[b][0];
        bf16x8 fa[8], fb[4];
#pragma unroll
        for (int ni = 0; ni < 4; ni++)
            fb[ni] = *(const bf16x8*)&Lb[rbw + (ni << 9) + phys];
#pragma unroll
        for (int mi = 0; mi < 8; mi++)
            fa[mi] = *(const bf16x8*)&Lb[raw + (mi << 9) + phys];
        STAGE(t + 2, bs);
        BAR;
        __builtin_amdgcn_s_setprio(1);
#pragma unroll
        for (int mi = 0; mi < 8; mi++)
#pragma unroll
            for (int ni = 0; ni < 4; ni++)
                acc[mi][ni] = __builtin_amdgcn_mfma_f32_16x16x32_bf16(
                    fa[mi], fb[ni], acc[mi][ni], 0, 0, 0);
        __builtin_amdgcn_s_setprio(0);
        if (t + 2 < nt) { VM4; } else { VM0; }   // publish tile t+1
        BAR; SB0;
        b = (b == 2) ? 0 : b + 1;
        bs = (bs == 2) ? 0 : bs + 1;
    }
#undef STAGE

    const int colbase = n0 + (wc << 6) + (lane & 15);
    if (mode == 2) {
        float* C = (float*)Cout;
#pragma unroll
        for (int mi = 0; mi < 8; mi++)
#pragma unroll
            for (int r = 0; r < 4; r++) {
                int m = m0 + (wr << 7) + (mi << 4) + ((lane >> 4) << 2) + r;
                float* row = C + (size_t)m * N + colbase;
#pragma unroll
                for (int ni = 0; ni < 4; ni++) row[ni << 4] = acc[mi][ni][r];
            }
    } else if (n0 < 2048) {                   // fused QKV: RoPE region (Q and K)
        u16* C = (u16*)Cout;
#pragma unroll
        for (int mi = 0; mi < 8; mi++)
#pragma unroll
            for (int r = 0; r < 4; r++) {
                int m = m0 + (wr << 7) + (mi << 4) + ((lane >> 4) << 2) + r;
                const float* cb = cosp + ((size_t)m << 6);
                const float* sb = sinp + ((size_t)m << 6);
                u16* row = C + (size_t)m * N + colbase;
#pragma unroll
                for (int ni = 0; ni < 4; ni++) {
                    int d = (ni << 4) + (lane & 15);   // head-dim pos (0..63)
                    float c = cb[d], s = sb[d];
                    float v0 = acc[mi][ni][r];
                    float vr = acc[mi][ni ^ 2][r];     // d +/- 32 partner
                    float o = fmaf(v0, c, (ni < 2 ? -vr : vr) * s);
                    row[ni << 4] = bf16u(o);
                }
            }
    } else {                                  // V region: plain bf16
        u16* C = (u16*)Cout;
#pragma unroll
        for (int mi = 0; mi < 8; mi++)
#pragma unroll
            for (int r = 0; r < 4; r++) {
                int m = m0 + (wr << 7) + (mi << 4) + ((lane >> 4) << 2) + r;
                u16* row = C + (size_t)m * N + colbase;
#pragma unroll
                for (int ni = 0; ni < 4; ni++) row[ni << 4] = bf16u(acc[mi][ni][r]);
            }
    }
}

// ------- axial attention, 48KB LDS (Pl overlays dead Kl), 3 blocks/CU ------
// sh layout: Kl @0 (16KB, dead after QK^T), VT @8192 (16KB, live through PV),
// Pl rows 0-63 @0 (over Kl), rows 64-127 @16384. Extra __syncthreads after
// QK^T guarantees all Kl reads complete before any P-store into sh[0..8191].
__global__ __launch_bounds__(256) void axial_attn(
    const u16* __restrict__ qkv, const float* __restrict__ mask,
    u16* __restrict__ cat)
{
    __shared__ u16 sh[24576];       // 48 KB
    const int hmode = blockIdx.x >> 11;
    const int o2 = blockIdx.x & 2047;
    const int b = (o2 & 7) * 256 + (o2 >> 3);   // per-half XCD chunk swizzle
    const int a = b >> 4, hd = b & 15;
    const int tid = threadIdx.x, wid = tid >> 6, lane = tid & 63;
    const int tmul = hmode ? 128 : 1;
    const int tadd = hmode ? a : (a << 7);
    const size_t hoff = (size_t)hd << 6;

    // ---- stage K into sh[0..8191] (XOR-swizzled source chunks, ^ row&7) ----
#pragma unroll
    for (int c = 0; c < 4; c++) {
        int row = (wid << 5) + (c << 3) + (lane >> 3);
        int sc = (lane & 7) ^ (row & 7);
        gl_lds16(qkv + (size_t)(row * tmul + tadd) * 3072 + 1024 + hoff + (sc << 3),
                 &sh[((wid << 5) + (c << 3)) << 6]);
    }
    // ---- stage V^T into sh[8192..16383] (reg transpose, swizzled ^ d&15) ----
#pragma unroll
    for (int i = 0; i < 4; i++) {
        int cid = tid + (i << 8);
        int j = cid >> 3;
        int d0 = (cid & 7) << 3;
        uint4 raw = *(const uint4*)(qkv + (size_t)(j * tmul + tadd) * 3072 + 2048 + hoff + d0);
        const u16* e = (const u16*)&raw;
#pragma unroll
        for (int t = 0; t < 8; t++) {
            int d = d0 + t;
            sh[8192 + (d << 7) + (((j >> 3) ^ (d & 15)) << 3) + (j & 7)] = e[t];
        }
    }
    bf16x8 aq[2][2];
#pragma unroll
    for (int qt = 0; qt < 2; qt++)
#pragma unroll
        for (int ks = 0; ks < 2; ks++) {
            int row = (wid << 5) + (qt << 4) + (lane & 15);
            aq[qt][ks] = *(const bf16x8*)(qkv + (size_t)(row * tmul + tadd) * 3072 + hoff
                                          + (ks << 5) + ((lane >> 4) << 3));
        }
    __syncthreads();

    f32x4 S[2][8] = {};
#pragma unroll
    for (int kt = 0; kt < 8; kt++) {
        bf16x8 bk[2];
#pragma unroll
        for (int ks = 0; ks < 2; ks++) {
            int row = (kt << 4) + (lane & 15);
            int ch = ((ks << 2) + (lane >> 4)) ^ (row & 7);
            bk[ks] = *(const bf16x8*)&sh[(row << 6) + (ch << 3)];
        }
#pragma unroll
        for (int qt = 0; qt < 2; qt++) {
            S[qt][kt] = __builtin_amdgcn_mfma_f32_16x16x32_bf16(aq[qt][0], bk[0], S[qt][kt], 0, 0, 0);
            S[qt][kt] = __builtin_amdgcn_mfma_f32_16x16x32_bf16(aq[qt][1], bk[1], S[qt][kt], 0, 0, 0);
        }
    }
    __syncthreads();   // all Kl reads done: sh[0..8191] is now free for Pl

    const float scale = 0.03125f;   // 1/sqrt(1024)
#pragma unroll
    for (int qt = 0; qt < 2; qt++) {
#pragma unroll
        for (int r = 0; r < 4; r++) {
            int qrow = (wid << 5) + (qt << 4) + ((lane >> 4) << 2) + r;
            const int plb = (qrow << 7) + ((qrow & 64) ? 8192 : 0);
            const float* mrow = mask + (hmode ? (a << 7) : (qrow << 7));
            float mx = -1e30f;
#pragma unroll
            for (int kt = 0; kt < 8; kt++) {
                float sv = fmaf(S[qt][kt][r], scale, mrow[(kt << 4) + (lane & 15)]);
                S[qt][kt][r] = sv;
                mx = fmaxf(mx, sv);
            }
            mx = fmaxf(mx, __shfl_xor(mx, 1));
            mx = fmaxf(mx, __shfl_xor(mx, 2));
            mx = fmaxf(mx, __shfl_xor(mx, 4));
            mx = fmaxf(mx, __shfl_xor(mx, 8));
            float sum = 0.f;
#pragma unroll
            for (int kt = 0; kt < 8; kt++) {
                float p = __expf(S[qt][kt][r] - mx);
                S[qt][kt][r] = p;
                sum += p;
            }
            sum += __shfl_xor(sum, 1);
            sum += __shfl_xor(sum, 2);
            sum += __shfl_xor(sum, 4);
            sum += __shfl_xor(sum, 8);
            float rinv = 1.0f / sum;
#pragma unroll
            for (int kt = 0; kt < 8; kt++) {
                int kcol = (kt << 4) + (lane & 15);
                int ch = (kcol >> 3) ^ (qrow & 15);
                sh[plb + (ch << 3) + (kcol & 7)] = bf16u(S[qt][kt][r] * rinv);
            }
        }
    }
    __syncthreads();

    f32x4 O[4][2] = {};
#pragma unroll
    for (int ks = 0; ks < 4; ks++) {
        bf16x8 av[4], bp[2];
#pragma unroll
        for (int qt = 0; qt < 2; qt++) {
            int qrow = (wid << 5) + (qt << 4) + (lane & 15);
            int ch = ((ks << 2) + (lane >> 4)) ^ (qrow & 15);
            bp[qt] = *(const bf16x8*)&sh[(qrow << 7) + ((qrow & 64) ? 8192 : 0) + (ch << 3)];
        }
#pragma unroll
        for (int dt = 0; dt < 4; dt++) {
            int drow = (dt << 4) + (lane & 15);
            int ch = ((ks << 2) + (lane >> 4)) ^ (drow & 15);
            av[dt] = *(const bf16x8*)&sh[8192 + (drow << 7) + (ch << 3)];
        }
#pragma unroll
        for (int dt = 0; dt < 4; dt++)
#pragma unroll
            for (int qt = 0; qt < 2; qt++)
                O[dt][qt] = __builtin_amdgcn_mfma_f32_16x16x32_bf16(av[dt], bp[qt], O[dt][qt], 0, 0, 0);
    }

    const int cbase = (hmode ? 1024 : 0) + (hd << 6);
#pragma unroll
    for (int dt = 0; dt < 4; dt++)
#pragma unroll
        for (int qt = 0; qt < 2; qt++) {
            int qrow = (wid << 5) + (qt << 4) + (lane & 15);
            int d0 = (dt << 4) + ((lane >> 4) << 2);
            size_t base = ((size_t)(qrow * tmul + tadd) << 11) + cbase + d0;
            ushort4 pk;
            pk.x = bf16u(O[dt][qt][0]);
            pk.y = bf16u(O[dt][qt][1]);
            pk.z = bf16u(O[dt][qt][2]);
            pk.w = bf16u(O[dt][qt][3]);
            *(ushort4*)(cat + base) = pk;
        }
}

extern "C" void kernel_launch(void* const* d_in, const int* in_sizes, int n_in,
                              void* d_out, int out_size, void* d_ws, size_t ws_size,
                              hipStream_t stream)
{
    (void)in_sizes; (void)n_in; (void)out_size; (void)ws_size;
    const float* hidden = (const float*)d_in[0];
    const float* mask   = (const float*)d_in[1];
    const float* cosp   = (const float*)d_in[2];
    const float* sinp   = (const float*)d_in[3];
    const float* Wq     = (const float*)d_in[4];
    const float* Wk     = (const float*)d_in[5];
    const float* Wv     = (const float*)d_in[6];
    const float* Wo     = (const float*)d_in[7];

    char* ws = (char*)d_ws;
    u16* Xb    = (u16*)(ws);                  // 33,554,432 B
    u16* WqkvT = (u16*)(ws + 33554432);       //  6,291,456 B
    u16* cat   = (u16*)(ws);                  // 67,108,864 B (reuse, stream-ordered)
    u16* WoT   = (u16*)(ws + 67108864);       //  4,194,304 B
    u16* qkvb  = (u16*)(ws + 71303168);       // 100,663,296 B

    prep_all<<<dim3(32, 64, 5), 256, 0, stream>>>(hidden, (ushort4*)Xb,
                                                  Wq, Wk, Wv, Wo, WqkvT, WoT);

    // fused QKV projection + RoPE: [16384,1024] x [1024,3072]  (pair-step)
    gemm_pp<<<dim3(24, 128), 256, 0, stream>>>(Xb, WqkvT, qkvb, cosp, sinp, 16384, 3072, 1024, 1);

    axial_attn<<<4096, 256, 0, stream>>>(qkvb, mask, cat);

    // output projection: [16384,2048] x [2048,1024] -> fp32  (fixed fat 256²)
    gemm_fat<<<dim3(4, 64), 512, 0, stream>>>(cat, WoT, d_out, nullptr, nullptr, 16384, 1024, 2048, 2);
}

// Round 16
// 301.270 us; speedup vs baseline: 1.6484x; 1.0385x over previous
//
#include <hip/hip_runtime.h>

typedef unsigned short u16;
typedef unsigned int   u32;
typedef __bf16 bf16;
typedef bf16  bf16x8 __attribute__((ext_vector_type(8)));
typedef float f32x4  __attribute__((ext_vector_type(4)));

__device__ __forceinline__ u16 bf16u(float f) {
    u32 x = __builtin_bit_cast(u32, f);
    x += 0x7fffu + ((x >> 16) & 1u);   // RNE
    return (u16)(x >> 16);
}

__device__ __forceinline__ void gl_lds16(const void* g, void* l) {
    __builtin_amdgcn_global_load_lds(
        (const __attribute__((address_space(1))) u32*)g,
        (__attribute__((address_space(3))) u32*)l, 16, 0, 0);
}

// ---- merged prep: fp32->bf16 convert (z==4) + 4 weight transposes (z<4) ----
__global__ __launch_bounds__(256) void prep_all(
    const float* __restrict__ hidden, ushort4* __restrict__ Xb,
    const float* __restrict__ Wq, const float* __restrict__ Wk,
    const float* __restrict__ Wv, const float* __restrict__ Wo,
    u16* __restrict__ WqkvT, u16* __restrict__ WoT)
{
    const int z = blockIdx.z;
    if (z == 4) {   // cvt: 2048 blocks x 8 float4-chunks of 256
        const float4* in = (const float4*)hidden;
        int b = blockIdx.y * 32 + blockIdx.x;
#pragma unroll
        for (int it = 0; it < 8; it++) {
            int i = (b << 11) + (it << 8) + threadIdx.x;
            float4 f = in[i];
            ushort4 o;
            o.x = bf16u(f.x); o.y = bf16u(f.y); o.z = bf16u(f.z); o.w = bf16u(f.w);
            Xb[i] = o;
        }
        return;
    }
    const float* W; u16* WT; int rows, cols;
    if (z < 3) {
        if (blockIdx.y >= 32) return;
        W = (z == 0) ? Wq : (z == 1) ? Wk : Wv;
        WT = WqkvT + (size_t)z * 1024 * 1024;
        rows = 1024; cols = 1024;
    } else {
        W = Wo; WT = WoT; rows = 2048; cols = 1024;
    }
    __shared__ float t[32][33];
    int bx = blockIdx.x * 32, by = blockIdx.y * 32;
    int x = threadIdx.x & 31, y = threadIdx.x >> 5;
#pragma unroll
    for (int i = 0; i < 32; i += 8)
        t[y + i][x] = W[(size_t)(by + y + i) * cols + bx + x];
    __syncthreads();
#pragma unroll
    for (int i = 0; i < 32; i += 8)
        WT[(size_t)(bx + y + i) * rows + by + x] = bf16u(t[x][y + i]);
}

#define BAR   __builtin_amdgcn_s_barrier()
#define SB0   __builtin_amdgcn_sched_barrier(0)
#define VM4   asm volatile("s_waitcnt vmcnt(4)" ::: "memory")
#define VM0   asm volatile("s_waitcnt vmcnt(0)" ::: "memory")

// 2D XCD chunking: XCD x owns (m-quarter = x>>1, n-half = x&1). Per-XCD B
// working set = (nx/2) n-panels -> 3.1 MB (QKV) / 2.1 MB (Wo) < 4 MB L2 ->
// B stays L2-resident; A read <=2x from HBM (two n-halves). Bijective:
// requires nx%2==0, ny%4==0, nwg%8==0 (all grids here satisfy).
#define XCD2D(SH) \
    const int nx = gridDim.x, ny = gridDim.y; \
    const int orig = blockIdx.y * nx + blockIdx.x; \
    const int xcd = orig & 7, idx = orig >> 3; \
    const int nxh = nx >> 1; \
    const int m0 = ((xcd >> 1) * (ny >> 2) + idx / nxh) << (SH); \
    const int n0 = ((xcd & 1) * nxh + idx % nxh) << (SH);

// ====== 128x128 GEMM, pair-step (r11/r13, measured 151.4us QKV) ======
// 4x16KB bufs, barrier-pair per 2 K-steps, 2 blocks/CU; grid 3072 blocks =
// 6.0 exact co-residency rounds. B-frags read first. 2D XCD chunking (r16).
__global__ __launch_bounds__(256, 2) void gemm_pp(
    const u16* __restrict__ A, const u16* __restrict__ BT, void* __restrict__ Cout,
    const float* __restrict__ cosp, const float* __restrict__ sinp,
    int M, int N, int K, int mode)
{
    __shared__ u16 Ld[4][8192];    // per buf: A @0 (4096 u16), B @4096 = 16 KB
    const int tid = threadIdx.x;
    const int wid = tid >> 6, lane = tid & 63;
    XCD2D(7)
    const int wr = wid >> 1, wc = wid & 1;

    const int srow = tid >> 2;                       // 0..63
    const int sg = (tid & 3) ^ ((srow >> 1) & 3);    // inverse-swizzled k-chunk
    const u16* aS = A + (size_t)(m0 + srow) * K + (sg << 3);
    const u16* bS = BT + (size_t)(n0 + srow) * K + (sg << 3);
    const size_t h64K = (size_t)64 * K;
    const int wdb = wid << 9;                        // wave-uniform dest (u16)
    const int nt = K >> 5;                           // even

#define STAGE(T) do { const int _b = (T) & 3; const size_t _ko = (size_t)(T) << 5; \
        gl_lds16(aS + _ko,        &Ld[_b][wdb]); \
        gl_lds16(aS + _ko + h64K, &Ld[_b][2048 + wdb]); \
        gl_lds16(bS + _ko,        &Ld[_b][4096 + wdb]); \
        gl_lds16(bS + _ko + h64K, &Ld[_b][6144 + wdb]); } while (0)

    const int phys = ((lane >> 4) ^ ((lane >> 1) & 3)) << 3;
    const int raw = ((wr << 6) + (lane & 15)) << 5;          // A row base (u16)
    const int rbw = (((wc << 6) + (lane & 15)) << 5) + 4096; // B row base (u16)

    f32x4 acc[4][4] = {};

    STAGE(0); STAGE(1);
    VM0; BAR;

    for (int t = 0; t < nt; t += 2) {
        if (t + 2 < nt) STAGE(t + 2);
        if (t + 3 < nt) STAGE(t + 3);
        {   // ---- K-step t ----
            const u16* Lb = &Ld[t & 3][0];
            bf16x8 af[4], bfr[4];
#pragma unroll
            for (int i = 0; i < 4; i++)
                bfr[i] = *(const bf16x8*)&Lb[rbw + (i << 9) + phys];
#pragma unroll
            for (int i = 0; i < 4; i++)
                af[i] = *(const bf16x8*)&Lb[raw + (i << 9) + phys];
            __builtin_amdgcn_s_setprio(1);
#pragma unroll
            for (int mi = 0; mi < 4; mi++)
#pragma unroll
                for (int ni = 0; ni < 4; ni++)
                    acc[mi][ni] = __builtin_amdgcn_mfma_f32_16x16x32_bf16(
                        af[mi], bfr[ni], acc[mi][ni], 0, 0, 0);
            __builtin_amdgcn_s_setprio(0);
        }
        {   // ---- K-step t+1 (buffer pre-published; reads overlap above MFMA) ----
            const u16* Lb = &Ld[(t + 1) & 3][0];
            bf16x8 af[4], bfr[4];
#pragma unroll
            for (int i = 0; i < 4; i++)
                bfr[i] = *(const bf16x8*)&Lb[rbw + (i << 9) + phys];
#pragma unroll
            for (int i = 0; i < 4; i++)
                af[i] = *(const bf16x8*)&Lb[raw + (i << 9) + phys];
            __builtin_amdgcn_s_setprio(1);
#pragma unroll
            for (int mi = 0; mi < 4; mi++)
#pragma unroll
                for (int ni = 0; ni < 4; ni++)
                    acc[mi][ni] = __builtin_amdgcn_mfma_f32_16x16x32_bf16(
                        af[mi], bfr[ni], acc[mi][ni], 0, 0, 0);
            __builtin_amdgcn_s_setprio(0);
        }
        VM0; BAR;
    }
#undef STAGE

    const int colbase = n0 + (wc << 6) + (lane & 15);
    if (mode == 2) {
        float* C = (float*)Cout;
#pragma unroll
        for (int mi = 0; mi < 4; mi++)
#pragma unroll
            for (int r = 0; r < 4; r++) {
                int m = m0 + (wr << 6) + (mi << 4) + ((lane >> 4) << 2) + r;
                float* row = C + (size_t)m * N + colbase;
#pragma unroll
                for (int ni = 0; ni < 4; ni++) row[ni << 4] = acc[mi][ni][r];
            }
    } else if (n0 < 2048) {                   // fused QKV: RoPE region (Q and K)
        u16* C = (u16*)Cout;
#pragma unroll
        for (int mi = 0; mi < 4; mi++)
#pragma unroll
            for (int r = 0; r < 4; r++) {
                int m = m0 + (wr << 6) + (mi << 4) + ((lane >> 4) << 2) + r;
                const float* cb = cosp + ((size_t)m << 6);
                const float* sb = sinp + ((size_t)m << 6);
                u16* row = C + (size_t)m * N + colbase;
#pragma unroll
                for (int ni = 0; ni < 4; ni++) {
                    int d = (ni << 4) + (lane & 15);   // head-dim pos (0..63)
                    float c = cb[d], s = sb[d];
                    float v0 = acc[mi][ni][r];
                    float vr = acc[mi][ni ^ 2][r];     // d +/- 32 partner
                    float o = fmaf(v0, c, (ni < 2 ? -vr : vr) * s);
                    row[ni << 4] = bf16u(o);
                }
            }
    } else {                                  // V region: plain bf16
        u16* C = (u16*)Cout;
#pragma unroll
        for (int mi = 0; mi < 4; mi++)
#pragma unroll
            for (int r = 0; r < 4; r++) {
                int m = m0 + (wr << 6) + (mi << 4) + ((lane >> 4) << 2) + r;
                u16* row = C + (size_t)m * N + colbase;
#pragma unroll
                for (int ni = 0; ni < 4; ni++) row[ni << 4] = bf16u(acc[mi][ni][r]);
            }
    }
}

// ====== 256x256 GEMM, fat-phase 3-buffer, read-order-fixed (r14 Wo) ======
__global__ __launch_bounds__(512, 2) void gemm_fat(
    const u16* __restrict__ A, const u16* __restrict__ BT, void* __restrict__ Cout,
    const float* __restrict__ cosp, const float* __restrict__ sinp,
    int M, int N, int K, int mode)
{
    __shared__ u16 Ld[3][16384];   // per buf: A @0 (8192 u16), B @8192
    const int tid = threadIdx.x;
    const int wid = tid >> 6, lane = tid & 63;
    XCD2D(8)
    const int wr = wid >> 2, wc = wid & 3;

    const int srow = tid >> 2;                     // row 0..127
    const int sl = (tid & 3) ^ ((srow >> 1) & 3);  // inverse-swizzled chunk
    const u16* aS0 = A + (size_t)(m0 + srow) * K + (sl << 3);
    const u16* aS1 = aS0 + (size_t)128 * K;
    const u16* bS0 = BT + (size_t)(n0 + srow) * K + (sl << 3);
    const u16* bS1 = bS0 + (size_t)128 * K;
    const int wdb = wid << 9;                      // wave-uniform dest (u16)
    const int nt = K >> 5;

#define STAGE(T, B_) do { if ((T) < nt) { size_t _ko = (size_t)(T) << 5; \
        gl_lds16(aS0 + _ko, &Ld[B_][wdb]); \
        gl_lds16(aS1 + _ko, &Ld[B_][4096 + wdb]); \
        gl_lds16(bS0 + _ko, &Ld[B_][8192 + wdb]); \
        gl_lds16(bS1 + _ko, &Ld[B_][12288 + wdb]); } } while (0)

    const int phys = ((lane >> 4) ^ ((lane >> 1) & 3)) << 3;   // u16 offset
    const int raw = ((wr << 7) + (lane & 15)) << 5;            // A row base (u16)
    const int rbw = (((wc << 6) + (lane & 15)) << 5) + 8192;   // B row base (u16)

    f32x4 acc[8][4] = {};

    STAGE(0, 0); STAGE(1, 1);
    VM4;                       // tile 0 landed; tile 1 (4 loads) in flight
    BAR; SB0;

    int b = 0, bs = 2;
    for (int t = 0; t < nt; ++t) {
        const u16* Lb = &Ld[b][0];
        bf16x8 fa[8], fb[4];
#pragma unroll
        for (int ni = 0; ni < 4; ni++)
            fb[ni] = *(const bf16x8*)&Lb[rbw + (ni << 9) + phys];
#pragma unroll
        for (int mi = 0; mi < 8; mi++)
            fa[mi] = *(const bf16x8*)&Lb[raw + (mi << 9) + phys];
        STAGE(t + 2, bs);
        BAR;
        __builtin_amdgcn_s_setprio(1);
#pragma unroll
        for (int mi = 0; mi < 8; mi++)
#pragma unroll
            for (int ni = 0; ni < 4; ni++)
                acc[mi][ni] = __builtin_amdgcn_mfma_f32_16x16x32_bf16(
                    fa[mi], fb[ni], acc[mi][ni], 0, 0, 0);
        __builtin_amdgcn_s_setprio(0);
        if (t + 2 < nt) { VM4; } else { VM0; }   // publish tile t+1
        BAR; SB0;
        b = (b == 2) ? 0 : b + 1;
        bs = (bs == 2) ? 0 : bs + 1;
    }
#undef STAGE

    const int colbase = n0 + (wc << 6) + (lane & 15);
    if (mode == 2) {
        float* C = (float*)Cout;
#pragma unroll
        for (int mi = 0; mi < 8; mi++)
#pragma unroll
            for (int r = 0; r < 4; r++) {
                int m = m0 + (wr << 7) + (mi << 4) + ((lane >> 4) << 2) + r;
                float* row = C + (size_t)m * N + colbase;
#pragma unroll
                for (int ni = 0; ni < 4; ni++) row[ni << 4] = acc[mi][ni][r];
            }
    } else if (n0 < 2048) {                   // fused QKV: RoPE region (Q and K)
        u16* C = (u16*)Cout;
#pragma unroll
        for (int mi = 0; mi < 8; mi++)
#pragma unroll
            for (int r = 0; r < 4; r++) {
                int m = m0 + (wr << 7) + (mi << 4) + ((lane >> 4) << 2) + r;
                const float* cb = cosp + ((size_t)m << 6);
                const float* sb = sinp + ((size_t)m << 6);
                u16* row = C + (size_t)m * N + colbase;
#pragma unroll
                for (int ni = 0; ni < 4; ni++) {
                    int d = (ni << 4) + (lane & 15);   // head-dim pos (0..63)
                    float c = cb[d], s = sb[d];
                    float v0 = acc[mi][ni][r];
                    float vr = acc[mi][ni ^ 2][r];     // d +/- 32 partner
                    float o = fmaf(v0, c, (ni < 2 ? -vr : vr) * s);
                    row[ni << 4] = bf16u(o);
                }
            }
    } else {                                  // V region: plain bf16
        u16* C = (u16*)Cout;
#pragma unroll
        for (int mi = 0; mi < 8; mi++)
#pragma unroll
            for (int r = 0; r < 4; r++) {
                int m = m0 + (wr << 7) + (mi << 4) + ((lane >> 4) << 2) + r;
                u16* row = C + (size_t)m * N + colbase;
#pragma unroll
                for (int ni = 0; ni < 4; ni++) row[ni << 4] = bf16u(acc[mi][ni][r]);
            }
    }
}

// ------- axial attention, 48KB LDS (Pl overlays dead Kl), 3 blocks/CU ------
// V-transpose staging: j-paired ds_write_b32 (halves write instrs, r16).
__global__ __launch_bounds__(256) void axial_attn(
    const u16* __restrict__ qkv, const float* __restrict__ mask,
    u16* __restrict__ cat)
{
    __shared__ u16 sh[24576];       // 48 KB
    const int hmode = blockIdx.x >> 11;
    const int o2 = blockIdx.x & 2047;
    const int b = (o2 & 7) * 256 + (o2 >> 3);   // per-half XCD chunk swizzle
    const int a = b >> 4, hd = b & 15;
    const int tid = threadIdx.x, wid = tid >> 6, lane = tid & 63;
    const int tmul = hmode ? 128 : 1;
    const int tadd = hmode ? a : (a << 7);
    const size_t hoff = (size_t)hd << 6;

    // ---- stage K into sh[0..8191] (XOR-swizzled source chunks, ^ row&7) ----
#pragma unroll
    for (int c = 0; c < 4; c++) {
        int row = (wid << 5) + (c << 3) + (lane >> 3);
        int sc = (lane & 7) ^ (row & 7);
        gl_lds16(qkv + (size_t)(row * tmul + tadd) * 3072 + 1024 + hoff + (sc << 3),
                 &sh[((wid << 5) + (c << 3)) << 6]);
    }
    // ---- stage V^T into sh[8192..16383] (j-paired b32 writes, swz ^ d&15) ----
#pragma unroll
    for (int i = 0; i < 2; i++) {
        int pid = tid + (i << 8);          // 0..511
        int j0 = (pid >> 3) << 1, j1 = j0 | 1;
        int d0 = (pid & 7) << 3;
        uint4 r0 = *(const uint4*)(qkv + (size_t)(j0 * tmul + tadd) * 3072 + 2048 + hoff + d0);
        uint4 r1 = *(const uint4*)(qkv + (size_t)(j1 * tmul + tadd) * 3072 + 2048 + hoff + d0);
        const u16* e0 = (const u16*)&r0;
        const u16* e1 = (const u16*)&r1;
        int g = j0 >> 3, lo = j0 & 7;      // j0 even: lo even -> 4B aligned
#pragma unroll
        for (int t = 0; t < 8; t++) {
            int d = d0 + t;
            *(u32*)&sh[8192 + (d << 7) + ((g ^ (d & 15)) << 3) + lo] =
                (u32)e0[t] | ((u32)e1[t] << 16);
        }
    }
    bf16x8 aq[2][2];
#pragma unroll
    for (int qt = 0; qt < 2; qt++)
#pragma unroll
        for (int ks = 0; ks < 2; ks++) {
            int row = (wid << 5) + (qt << 4) + (lane & 15);
            aq[qt][ks] = *(const bf16x8*)(qkv + (size_t)(row * tmul + tadd) * 3072 + hoff
                                          + (ks << 5) + ((lane >> 4) << 3));
        }
    __syncthreads();

    f32x4 S[2][8] = {};
#pragma unroll
    for (int kt = 0; kt < 8; kt++) {
        bf16x8 bk[2];
#pragma unroll
        for (int ks = 0; ks < 2; ks++) {
            int row = (kt << 4) + (lane & 15);
            int ch = ((ks << 2) + (lane >> 4)) ^ (row & 7);
            bk[ks] = *(const bf16x8*)&sh[(row << 6) + (ch << 3)];
        }
#pragma unroll
        for (int qt = 0; qt < 2; qt++) {
            S[qt][kt] = __builtin_amdgcn_mfma_f32_16x16x32_bf16(aq[qt][0], bk[0], S[qt][kt], 0, 0, 0);
            S[qt][kt] = __builtin_amdgcn_mfma_f32_16x16x32_bf16(aq[qt][1], bk[1], S[qt][kt], 0, 0, 0);
        }
    }
    __syncthreads();   // all Kl reads done: sh[0..8191] is now free for Pl

    const float scale = 0.03125f;   // 1/sqrt(1024)
#pragma unroll
    for (int qt = 0; qt < 2; qt++) {
#pragma unroll
        for (int r = 0; r < 4; r++) {
            int qrow = (wid << 5) + (qt << 4) + ((lane >> 4) << 2) + r;
            const int plb = (qrow << 7) + ((qrow & 64) ? 8192 : 0);
            const float* mrow = mask + (hmode ? (a << 7) : (qrow << 7));
            float mx = -1e30f;
#pragma unroll
            for (int kt = 0; kt < 8; kt++) {
                float sv = fmaf(S[qt][kt][r], scale, mrow[(kt << 4) + (lane & 15)]);
                S[qt][kt][r] = sv;
                mx = fmaxf(mx, sv);
            }
            mx = fmaxf(mx, __shfl_xor(mx, 1));
            mx = fmaxf(mx, __shfl_xor(mx, 2));
            mx = fmaxf(mx, __shfl_xor(mx, 4));
            mx = fmaxf(mx, __shfl_xor(mx, 8));
            float sum = 0.f;
#pragma unroll
            for (int kt = 0; kt < 8; kt++) {
                float p = __expf(S[qt][kt][r] - mx);
                S[qt][kt][r] = p;
                sum += p;
            }
            sum += __shfl_xor(sum, 1);
            sum += __shfl_xor(sum, 2);
            sum += __shfl_xor(sum, 4);
            sum += __shfl_xor(sum, 8);
            float rinv = 1.0f / sum;
#pragma unroll
            for (int kt = 0; kt < 8; kt++) {
                int kcol = (kt << 4) + (lane & 15);
                int ch = (kcol >> 3) ^ (qrow & 15);
                sh[plb + (ch << 3) + (kcol & 7)] = bf16u(S[qt][kt][r] * rinv);
            }
        }
    }
    __syncthreads();

    f32x4 O[4][2] = {};
#pragma unroll
    for (int ks = 0; ks < 4; ks++) {
        bf16x8 av[4], bp[2];
#pragma unroll
        for (int qt = 0; qt < 2; qt++) {
            int qrow = (wid << 5) + (qt << 4) + (lane & 15);
            int ch = ((ks << 2) + (lane >> 4)) ^ (qrow & 15);
            bp[qt] = *(const bf16x8*)&sh[(qrow << 7) + ((qrow & 64) ? 8192 : 0) + (ch << 3)];
        }
#pragma unroll
        for (int dt = 0; dt < 4; dt++) {
            int drow = (dt << 4) + (lane & 15);
            int ch = ((ks << 2) + (lane >> 4)) ^ (drow & 15);
            av[dt] = *(const bf16x8*)&sh[8192 + (drow << 7) + (ch << 3)];
        }
#pragma unroll
        for (int dt = 0; dt < 4; dt++)
#pragma unroll
            for (int qt = 0; qt < 2; qt++)
                O[dt][qt] = __builtin_amdgcn_mfma_f32_16x16x32_bf16(av[dt], bp[qt], O[dt][qt], 0, 0, 0);
    }

    const int cbase = (hmode ? 1024 : 0) + (hd << 6);
#pragma unroll
    for (int dt = 0; dt < 4; dt++)
#pragma unroll
        for (int qt = 0; qt < 2; qt++) {
            int qrow = (wid << 5) + (qt << 4) + (lane & 15);
            int d0 = (dt << 4) + ((lane >> 4) << 2);
            size_t base = ((size_t)(qrow * tmul + tadd) << 11) + cbase + d0;
            ushort4 pk;
            pk.x = bf16u(O[dt][qt][0]);
            pk.y = bf16u(O[dt][qt][1]);
            pk.z = bf16u(O[dt][qt][2]);
            pk.w = bf16u(O[dt][qt][3]);
            *(ushort4*)(cat + base) = pk;
        }
}

extern "C" void kernel_launch(void* const* d_in, const int* in_sizes, int n_in,
                              void* d_out, int out_size, void* d_ws, size_t ws_size,
                              hipStream_t stream)
{
    (void)in_sizes; (void)n_in; (void)out_size; (void)ws_size;
    const float* hidden = (const float*)d_in[0];
    const float* mask   = (const float*)d_in[1];
    const float* cosp   = (const float*)d_in[2];
    const float* sinp   = (const float*)d_in[3];
    const float* Wq     = (const float*)d_in[4];
    const float* Wk     = (const float*)d_in[5];
    const float* Wv     = (const float*)d_in[6];
    const float* Wo     = (const float*)d_in[7];

    char* ws = (char*)d_ws;
    u16* Xb    = (u16*)(ws);                  // 33,554,432 B
    u16* WqkvT = (u16*)(ws + 33554432);       //  6,291,456 B
    u16* cat   = (u16*)(ws);                  // 67,108,864 B (reuse, stream-ordered)
    u16* WoT   = (u16*)(ws + 67108864);       //  4,194,304 B
    u16* qkvb  = (u16*)(ws + 71303168);       // 100,663,296 B

    prep_all<<<dim3(32, 64, 5), 256, 0, stream>>>(hidden, (ushort4*)Xb,
                                                  Wq, Wk, Wv, Wo, WqkvT, WoT);

    // fused QKV projection + RoPE: [16384,1024] x [1024,3072]  (pair-step)
    gemm_pp<<<dim3(24, 128), 256, 0, stream>>>(Xb, WqkvT, qkvb, cosp, sinp, 16384, 3072, 1024, 1);

    axial_attn<<<4096, 256, 0, stream>>>(qkvb, mask, cat);

    // output projection: [16384,2048] x [2048,1024] -> fp32  (fixed fat 256²)
    gemm_fat<<<dim3(4, 64), 512, 0, stream>>>(cat, WoT, d_out, nullptr, nullptr, 16384, 1024, 2048, 2);
}

// Round 17
// 297.651 us; speedup vs baseline: 1.6685x; 1.0122x over previous
//
#include <hip/hip_runtime.h>

typedef unsigned short u16;
typedef unsigned int   u32;
typedef __bf16 bf16;
typedef bf16  bf16x8 __attribute__((ext_vector_type(8)));
typedef float f32x4  __attribute__((ext_vector_type(4)));

__device__ __forceinline__ u16 bf16u(float f) {
    u32 x = __builtin_bit_cast(u32, f);
    x += 0x7fffu + ((x >> 16) & 1u);   // RNE
    return (u16)(x >> 16);
}

__device__ __forceinline__ void gl_lds16(const void* g, void* l) {
    __builtin_amdgcn_global_load_lds(
        (const __attribute__((address_space(1))) u32*)g,
        (__attribute__((address_space(3))) u32*)l, 16, 0, 0);
}

// ---- merged prep: fp32->bf16 convert (z==4) + 4 weight transposes (z<4) ----
__global__ __launch_bounds__(256) void prep_all(
    const float* __restrict__ hidden, ushort4* __restrict__ Xb,
    const float* __restrict__ Wq, const float* __restrict__ Wk,
    const float* __restrict__ Wv, const float* __restrict__ Wo,
    u16* __restrict__ WqkvT, u16* __restrict__ WoT)
{
    const int z = blockIdx.z;
    if (z == 4) {   // cvt: 2048 blocks x 8 float4-chunks of 256
        const float4* in = (const float4*)hidden;
        int b = blockIdx.y * 32 + blockIdx.x;
#pragma unroll
        for (int it = 0; it < 8; it++) {
            int i = (b << 11) + (it << 8) + threadIdx.x;
            float4 f = in[i];
            ushort4 o;
            o.x = bf16u(f.x); o.y = bf16u(f.y); o.z = bf16u(f.z); o.w = bf16u(f.w);
            Xb[i] = o;
        }
        return;
    }
    const float* W; u16* WT; int rows, cols;
    if (z < 3) {
        if (blockIdx.y >= 32) return;
        W = (z == 0) ? Wq : (z == 1) ? Wk : Wv;
        WT = WqkvT + (size_t)z * 1024 * 1024;
        rows = 1024; cols = 1024;
    } else {
        W = Wo; WT = WoT; rows = 2048; cols = 1024;
    }
    __shared__ float t[32][33];
    int bx = blockIdx.x * 32, by = blockIdx.y * 32;
    int x = threadIdx.x & 31, y = threadIdx.x >> 5;
#pragma unroll
    for (int i = 0; i < 32; i += 8)
        t[y + i][x] = W[(size_t)(by + y + i) * cols + bx + x];
    __syncthreads();
#pragma unroll
    for (int i = 0; i < 32; i += 8)
        WT[(size_t)(bx + y + i) * rows + by + x] = bf16u(t[x][y + i]);
}

#define BAR   __builtin_amdgcn_s_barrier()
#define SB0   __builtin_amdgcn_sched_barrier(0)
#define VM6   asm volatile("s_waitcnt vmcnt(6)" ::: "memory")
#define VM0   asm volatile("s_waitcnt vmcnt(0)" ::: "memory")

// 2D XCD chunking with separate m/n shifts: XCD x owns (m-quarter, n-half).
// Per-XCD B working set < 4 MB L2 -> B L2-resident; A read <=2x from HBM.
// Bijective: requires nx%2==0, ny%4==0 (all grids here satisfy).
#define XCD2D2(SHM, SHN) \
    const int nx = gridDim.x, ny = gridDim.y; \
    const int orig = blockIdx.y * nx + blockIdx.x; \
    const int xcd = orig & 7, idx = orig >> 3; \
    const int nxh = nx >> 1; \
    const int m0 = ((xcd >> 1) * (ny >> 2) + idx / nxh) << (SHM); \
    const int n0 = ((xcd & 1) * nxh + idx % nxh) << (SHN);

// ====== 128x256 GEMM, wide-N wave tile, fat-rotation 3-buffer (r17) ======
// 256 thr = 4 waves (2M x 2N), wave tile 64x128 (4 A-frags x 8 B-frags = 32
// MFMA per phase per wave; 29 FLOP/LDS-byte vs 64x64's 21.9 — LDS pipe is the
// measured limiter at ~750cy vs 155cy MFMA per pp-block-K-step).
// LDS: 3 bufs x (A[128][32] @0 + B[256][32] @4096) = 3 x 24 KB = 72 KB ->
// 2 blocks/CU. Phase t: {8 B-frag reads, 4 A-frag reads | STAGE(t+2) 6 gl_lds}
// BAR; 32 MFMA (setprio, mi-outer); publish t+1 via VM6 (t+2's 6 stay in
// flight); BAR; SB0. Single stage-point/phase -> vmcnt order == tile order
// (proven fat skeleton: r7/r12-r16 Wo). Rotation safety: buf (t+2)%3 was last
// read in phase t-1, whose closing BAR precedes this phase's STAGE.
// Chunk swizzle (0-conflict, verified): slot s at row r holds global k-chunk
// s^((r>>1)&3); inverse on gl_lds SOURCE, forward on ds_read (rule 21).
// mode 1: bf16 out + fused RoPE when col<2048 (head = ni>>2, partner = ni^2).
// mode 2: fp32 out.
__global__ __launch_bounds__(256, 2) void gemm_wn(
    const u16* __restrict__ A, const u16* __restrict__ BT, void* __restrict__ Cout,
    const float* __restrict__ cosp, const float* __restrict__ sinp,
    int M, int N, int K, int mode)
{
    __shared__ u16 Ld[3][12288];   // per buf: A @0 (4096 u16), B @4096 (8192 u16)
    const int tid = threadIdx.x;
    const int wid = tid >> 6, lane = tid & 63;
    XCD2D2(7, 8)
    const int wr = wid >> 1, wc = wid & 1;

    // staging: A chunks c=tid (rows 0-63), c=tid+256 (rows 64-127);
    // B chunks c=tid+256g, g=0..3 (rows srow+64g). slot=tid&3, same inverse
    // swizzle for all groups (64g doesn't touch row bits 1-2 mod 4).
    const int srow = tid >> 2;                       // 0..63
    const int sg = (tid & 3) ^ ((srow >> 1) & 3);    // inverse-swizzled k-chunk
    const u16* aS = A + (size_t)(m0 + srow) * K + (sg << 3);
    const u16* bS = BT + (size_t)(n0 + srow) * K + (sg << 3);
    const size_t h64K = (size_t)64 * K;
    const int wdb = wid << 9;                        // wave-uniform dest (u16)
    const int nt = K >> 5;

#define STAGE(T, B_) do { if ((T) < nt) { const size_t _ko = (size_t)(T) << 5; \
        gl_lds16(aS + _ko,            &Ld[B_][wdb]); \
        gl_lds16(aS + _ko + h64K,     &Ld[B_][2048 + wdb]); \
        gl_lds16(bS + _ko,            &Ld[B_][4096 + wdb]); \
        gl_lds16(bS + _ko + h64K,     &Ld[B_][6144 + wdb]); \
        gl_lds16(bS + _ko + 2 * h64K, &Ld[B_][8192 + wdb]); \
        gl_lds16(bS + _ko + 3 * h64K, &Ld[B_][10240 + wdb]); } } while (0)

    // frag reads: phys chunk = (lane>>4)^((lane>>1)&3) (row bits 1-2 == lane
    // bits 1-2 since row steps are multiples of 16)
    const int phys = ((lane >> 4) ^ ((lane >> 1) & 3)) << 3;
    const int raw = ((wr << 6) + (lane & 15)) << 5;            // A row base
    const int rbw = 4096 + (((wc << 7) + (lane & 15)) << 5);   // B row base

    f32x4 acc[4][8] = {};

    STAGE(0, 0); STAGE(1, 1);
    VM6;                       // tile 0 landed; tile 1 (6 loads) in flight
    BAR; SB0;

    int b = 0, bs = 2;
    for (int t = 0; t < nt; ++t) {
        const u16* Lb = &Ld[b][0];
        bf16x8 fa[4], fb[8];
#pragma unroll
        for (int ni = 0; ni < 8; ni++)
            fb[ni] = *(const bf16x8*)&Lb[rbw + (ni << 9) + phys];
#pragma unroll
        for (int mi = 0; mi < 4; mi++)
            fa[mi] = *(const bf16x8*)&Lb[raw + (mi << 9) + phys];
        STAGE(t + 2, bs);
        BAR;
        __builtin_amdgcn_s_setprio(1);
#pragma unroll
        for (int mi = 0; mi < 4; mi++)
#pragma unroll
            for (int ni = 0; ni < 8; ni++)
                acc[mi][ni] = __builtin_amdgcn_mfma_f32_16x16x32_bf16(
                    fa[mi], fb[ni], acc[mi][ni], 0, 0, 0);
        __builtin_amdgcn_s_setprio(0);
        if (t + 2 < nt) { VM6; } else { VM0; }   // publish tile t+1
        BAR; SB0;
        b = (b == 2) ? 0 : b + 1;
        bs = (bs == 2) ? 0 : bs + 1;
    }
#undef STAGE

    const int colbase = n0 + (wc << 7) + (lane & 15);
    if (mode == 2) {
        float* C = (float*)Cout;
#pragma unroll
        for (int mi = 0; mi < 4; mi++)
#pragma unroll
            for (int r = 0; r < 4; r++) {
                int m = m0 + (wr << 6) + (mi << 4) + ((lane >> 4) << 2) + r;
                float* row = C + (size_t)m * N + colbase;
#pragma unroll
                for (int ni = 0; ni < 8; ni++) row[ni << 4] = acc[mi][ni][r];
            }
    } else if (n0 < 2048) {                   // fused QKV: RoPE region (Q and K)
        u16* C = (u16*)Cout;
#pragma unroll
        for (int mi = 0; mi < 4; mi++)
#pragma unroll
            for (int r = 0; r < 4; r++) {
                int m = m0 + (wr << 6) + (mi << 4) + ((lane >> 4) << 2) + r;
                const float* cb = cosp + ((size_t)m << 6);
                const float* sb = sinp + ((size_t)m << 6);
                u16* row = C + (size_t)m * N + colbase;
#pragma unroll
                for (int ni = 0; ni < 8; ni++) {
                    int d = ((ni & 3) << 4) + (lane & 15); // head-dim pos 0..63
                    float c = cb[d], s = sb[d];
                    float v0 = acc[mi][ni][r];
                    float vr = acc[mi][ni ^ 2][r];         // d +/- 32, same head
                    float o = fmaf(v0, c, ((ni & 3) < 2 ? -vr : vr) * s);
                    row[ni << 4] = bf16u(o);
                }
            }
    } else {                                  // V region: plain bf16
        u16* C = (u16*)Cout;
#pragma unroll
        for (int mi = 0; mi < 4; mi++)
#pragma unroll
            for (int r = 0; r < 4; r++) {
                int m = m0 + (wr << 6) + (mi << 4) + ((lane >> 4) << 2) + r;
                u16* row = C + (size_t)m * N + colbase;
#pragma unroll
                for (int ni = 0; ni < 8; ni++) row[ni << 4] = bf16u(acc[mi][ni][r]);
            }
    }
}

// ------- axial attention, 48KB LDS (Pl overlays dead Kl), 3 blocks/CU ------
// V-transpose staging: j-paired ds_write_b32 (halves write instrs, r16).
__global__ __launch_bounds__(256) void axial_attn(
    const u16* __restrict__ qkv, const float* __restrict__ mask,
    u16* __restrict__ cat)
{
    __shared__ u16 sh[24576];       // 48 KB
    const int hmode = blockIdx.x >> 11;
    const int o2 = blockIdx.x & 2047;
    const int b = (o2 & 7) * 256 + (o2 >> 3);   // per-half XCD chunk swizzle
    const int a = b >> 4, hd = b & 15;
    const int tid = threadIdx.x, wid = tid >> 6, lane = tid & 63;
    const int tmul = hmode ? 128 : 1;
    const int tadd = hmode ? a : (a << 7);
    const size_t hoff = (size_t)hd << 6;

    // ---- stage K into sh[0..8191] (XOR-swizzled source chunks, ^ row&7) ----
#pragma unroll
    for (int c = 0; c < 4; c++) {
        int row = (wid << 5) + (c << 3) + (lane >> 3);
        int sc = (lane & 7) ^ (row & 7);
        gl_lds16(qkv + (size_t)(row * tmul + tadd) * 3072 + 1024 + hoff + (sc << 3),
                 &sh[((wid << 5) + (c << 3)) << 6]);
    }
    // ---- stage V^T into sh[8192..16383] (j-paired b32 writes, swz ^ d&15) ----
#pragma unroll
    for (int i = 0; i < 2; i++) {
        int pid = tid + (i << 8);          // 0..511
        int j0 = (pid >> 3) << 1, j1 = j0 | 1;
        int d0 = (pid & 7) << 3;
        uint4 r0 = *(const uint4*)(qkv + (size_t)(j0 * tmul + tadd) * 3072 + 2048 + hoff + d0);
        uint4 r1 = *(const uint4*)(qkv + (size_t)(j1 * tmul + tadd) * 3072 + 2048 + hoff + d0);
        const u16* e0 = (const u16*)&r0;
        const u16* e1 = (const u16*)&r1;
        int g = j0 >> 3, lo = j0 & 7;      // j0 even: lo even -> 4B aligned
#pragma unroll
        for (int t = 0; t < 8; t++) {
            int d = d0 + t;
            *(u32*)&sh[8192 + (d << 7) + ((g ^ (d & 15)) << 3) + lo] =
                (u32)e0[t] | ((u32)e1[t] << 16);
        }
    }
    bf16x8 aq[2][2];
#pragma unroll
    for (int qt = 0; qt < 2; qt++)
#pragma unroll
        for (int ks = 0; ks < 2; ks++) {
            int row = (wid << 5) + (qt << 4) + (lane & 15);
            aq[qt][ks] = *(const bf16x8*)(qkv + (size_t)(row * tmul + tadd) * 3072 + hoff
                                          + (ks << 5) + ((lane >> 4) << 3));
        }
    __syncthreads();

    f32x4 S[2][8] = {};
#pragma unroll
    for (int kt = 0; kt < 8; kt++) {
        bf16x8 bk[2];
#pragma unroll
        for (int ks = 0; ks < 2; ks++) {
            int row = (kt << 4) + (lane & 15);
            int ch = ((ks << 2) + (lane >> 4)) ^ (row & 7);
            bk[ks] = *(const bf16x8*)&sh[(row << 6) + (ch << 3)];
        }
#pragma unroll
        for (int qt = 0; qt < 2; qt++) {
            S[qt][kt] = __builtin_amdgcn_mfma_f32_16x16x32_bf16(aq[qt][0], bk[0], S[qt][kt], 0, 0, 0);
            S[qt][kt] = __builtin_amdgcn_mfma_f32_16x16x32_bf16(aq[qt][1], bk[1], S[qt][kt], 0, 0, 0);
        }
    }
    __syncthreads();   // all Kl reads done: sh[0..8191] is now free for Pl

    const float scale = 0.03125f;   // 1/sqrt(1024)
#pragma unroll
    for (int qt = 0; qt < 2; qt++) {
#pragma unroll
        for (int r = 0; r < 4; r++) {
            int qrow = (wid << 5) + (qt << 4) + ((lane >> 4) << 2) + r;
            const int plb = (qrow << 7) + ((qrow & 64) ? 8192 : 0);
            const float* mrow = mask + (hmode ? (a << 7) : (qrow << 7));
            float mx = -1e30f;
#pragma unroll
            for (int kt = 0; kt < 8; kt++) {
                float sv = fmaf(S[qt][kt][r], scale, mrow[(kt << 4) + (lane & 15)]);
                S[qt][kt][r] = sv;
                mx = fmaxf(mx, sv);
            }
            mx = fmaxf(mx, __shfl_xor(mx, 1));
            mx = fmaxf(mx, __shfl_xor(mx, 2));
            mx = fmaxf(mx, __shfl_xor(mx, 4));
            mx = fmaxf(mx, __shfl_xor(mx, 8));
            float sum = 0.f;
#pragma unroll
            for (int kt = 0; kt < 8; kt++) {
                float p = __expf(S[qt][kt][r] - mx);
                S[qt][kt][r] = p;
                sum += p;
            }
            sum += __shfl_xor(sum, 1);
            sum += __shfl_xor(sum, 2);
            sum += __shfl_xor(sum, 4);
            sum += __shfl_xor(sum, 8);
            float rinv = 1.0f / sum;
#pragma unroll
            for (int kt = 0; kt < 8; kt++) {
                int kcol = (kt << 4) + (lane & 15);
                int ch = (kcol >> 3) ^ (qrow & 15);
                sh[plb + (ch << 3) + (kcol & 7)] = bf16u(S[qt][kt][r] * rinv);
            }
        }
    }
    __syncthreads();

    f32x4 O[4][2] = {};
#pragma unroll
    for (int ks = 0; ks < 4; ks++) {
        bf16x8 av[4], bp[2];
#pragma unroll
        for (int qt = 0; qt < 2; qt++) {
            int qrow = (wid << 5) + (qt << 4) + (lane & 15);
            int ch = ((ks << 2) + (lane >> 4)) ^ (qrow & 15);
            bp[qt] = *(const bf16x8*)&sh[(qrow << 7) + ((qrow & 64) ? 8192 : 0) + (ch << 3)];
        }
#pragma unroll
        for (int dt = 0; dt < 4; dt++) {
            int drow = (dt << 4) + (lane & 15);
            int ch = ((ks << 2) + (lane >> 4)) ^ (drow & 15);
            av[dt] = *(const bf16x8*)&sh[8192 + (drow << 7) + (ch << 3)];
        }
#pragma unroll
        for (int dt = 0; dt < 4; dt++)
#pragma unroll
            for (int qt = 0; qt < 2; qt++)
                O[dt][qt] = __builtin_amdgcn_mfma_f32_16x16x32_bf16(av[dt], bp[qt], O[dt][qt], 0, 0, 0);
    }

    const int cbase = (hmode ? 1024 : 0) + (hd << 6);
#pragma unroll
    for (int dt = 0; dt < 4; dt++)
#pragma unroll
        for (int qt = 0; qt < 2; qt++) {
            int qrow = (wid << 5) + (qt << 4) + (lane & 15);
            int d0 = (dt << 4) + ((lane >> 4) << 2);
            size_t base = ((size_t)(qrow * tmul + tadd) << 11) + cbase + d0;
            ushort4 pk;
            pk.x = bf16u(O[dt][qt][0]);
            pk.y = bf16u(O[dt][qt][1]);
            pk.z = bf16u(O[dt][qt][2]);
            pk.w = bf16u(O[dt][qt][3]);
            *(ushort4*)(cat + base) = pk;
        }
}

extern "C" void kernel_launch(void* const* d_in, const int* in_sizes, int n_in,
                              void* d_out, int out_size, void* d_ws, size_t ws_size,
                              hipStream_t stream)
{
    (void)in_sizes; (void)n_in; (void)out_size; (void)ws_size;
    const float* hidden = (const float*)d_in[0];
    const float* mask   = (const float*)d_in[1];
    const float* cosp   = (const float*)d_in[2];
    const float* sinp   = (const float*)d_in[3];
    const float* Wq     = (const float*)d_in[4];
    const float* Wk     = (const float*)d_in[5];
    const float* Wv     = (const float*)d_in[6];
    const float* Wo     = (const float*)d_in[7];

    char* ws = (char*)d_ws;
    u16* Xb    = (u16*)(ws);                  // 33,554,432 B
    u16* WqkvT = (u16*)(ws + 33554432);       //  6,291,456 B
    u16* cat   = (u16*)(ws);                  // 67,108,864 B (reuse, stream-ordered)
    u16* WoT   = (u16*)(ws + 67108864);       //  4,194,304 B
    u16* qkvb  = (u16*)(ws + 71303168);       // 100,663,296 B

    prep_all<<<dim3(32, 64, 5), 256, 0, stream>>>(hidden, (ushort4*)Xb,
                                                  Wq, Wk, Wv, Wo, WqkvT, WoT);

    // fused QKV projection + RoPE: [16384,1024] x [1024,3072]  (wide-N, 3.0 rounds)
    gemm_wn<<<dim3(12, 128), 256, 0, stream>>>(Xb, WqkvT, qkvb, cosp, sinp, 16384, 3072, 1024, 1);

    axial_attn<<<4096, 256, 0, stream>>>(qkvb, mask, cat);

    // output projection: [16384,2048] x [2048,1024] -> fp32  (wide-N, 1.0 round)
    gemm_wn<<<dim3(4, 128), 256, 0, stream>>>(cat, WoT, d_out, nullptr, nullptr, 16384, 1024, 2048, 2);
}